// Round 7
// baseline (127.072 us; speedup 1.0000x reference)
//
#include <hip/hip_runtime.h>

typedef float f32x4 __attribute__((ext_vector_type(4)));
typedef short bf16x8 __attribute__((ext_vector_type(8)));

#define MFMA16(a,b,c) __builtin_amdgcn_mfma_f32_16x16x32_bf16((a),(b),(c),0,0,0)

__device__ __forceinline__ unsigned short f2bf(float f){
  unsigned int u = __builtin_bit_cast(unsigned int, f);
  u += 0x7FFFu + ((u>>16)&1u);
  return (unsigned short)(u>>16);
}
__device__ __forceinline__ float bf2f(unsigned short u){
  return __builtin_bit_cast(float, ((unsigned int)u)<<16);
}

// ---------------- ws layout (bytes) ----------------
#define OFF_SNBF  0u          // 512*384*2      = 393216
#define OFF_PROJ  393216u     // 512*1152*4     = 2359296
#define OFF_QP    2752512u    // 512*144*4      = 294912
#define OFF_KFRAG 3047424u    // 12*32*64*8*2   = 393216
#define OFF_VFRAG 3440640u    // 12*16*3*64*8*2 = 589824
#define OFF_KN2   4030464u    // 12*512*4       = 24576
#define OFF_PLT   4055040u    // 12*32*512*16*2 = 6291456 (bf16, tiled [h][ib][j][16])
#define OFF_OBUF  10346496u   // 512*480*4      = 983040
#define OFF_WCF   11329536u   // 72*12*64*8*2   = 884736
#define OFF_WOF   12214272u   // 24*18*64*8*2   = 442368
#define OFF_WBUF  12656640u   // 12*4 (pad 256)

// ---- pairbias helpers ----
__device__ __forceinline__ void pb_frags(const float* __restrict__ Wpb,
    const float* __restrict__ g_z, const float* __restrict__ b_z,
    int il, int ig, bf16x8* gzb, bf16x8* bzb, bf16x8* wf){
  #pragma unroll
  for (int c=0;c<4;c++){
    #pragma unroll
    for (int r=0;r<8;r++){
      int cc = c*32 + ig*8 + r;
      gzb[c][r] = (short)f2bf(g_z[cc]);
      bzb[c][r] = (short)f2bf(b_z[cc]);
      wf[c][r]  = (il<12) ? (short)f2bf(Wpb[cc*12 + il]) : (short)0;
    }
  }
}

// unit g: i = g & 511 (one s-row), jb = g >> 9 (16-j block). z tile is the
// contiguous 8 KB block z[i][jb*16 .. jb*16+16][*]; rows are j (512 B apart).
__device__ __forceinline__ void pb_unit(int g, const float* __restrict__ z,
    unsigned short* __restrict__ plTbf, int il, int ig,
    const bf16x8* gzb, const bf16x8* bzb, const bf16x8* wf){
  int i = g & 511; int jb = g >> 9;
  const float* zr = z + ((size_t)i*512 + jb*16)*128;
  // lane (il=jl, ig) holds row j'=il, floats c*32+ig*8 .. +8
  f32x4 zv[8];
  #pragma unroll
  for (int c=0;c<4;c++){
    zv[2*c]   = *(const f32x4*)(zr + il*128 + c*32 + ig*8);
    zv[2*c+1] = *(const f32x4*)(zr + il*128 + c*32 + ig*8 + 4);
  }
  float sum=0.f, ss=0.f;
  #pragma unroll
  for (int m=0;m<8;m++)
    #pragma unroll
    for (int e=0;e<4;e++){ float x = zv[m][e]; sum += x; ss = fmaf(x,x,ss); }
  sum += __shfl_xor(sum,16); sum += __shfl_xor(sum,32);
  ss  += __shfl_xor(ss,16);  ss  += __shfl_xor(ss,32);
  float mu  = sum*(1.f/128.f);
  float var = ss*(1.f/128.f) - mu*mu;
  float rs  = rsqrtf(var + 1e-5f);
  f32x4 acc = {0.f,0.f,0.f,0.f};
  #pragma unroll
  for (int c=0;c<4;c++){
    bf16x8 zf;
    #pragma unroll
    for (int r=0;r<8;r++){
      float xv = (r<4)? zv[2*c][r&3] : zv[2*c+1][r&3];
      float gv = bf2f((unsigned short)gzb[c][r]);
      float bv = bf2f((unsigned short)bzb[c][r]);
      zf[r] = (short)f2bf((xv-mu)*(rs*gv) + bv);
    }
    acc = MFMA16(zf, wf[c], acc);
  }
  // C[j'][h]: lane holds col h=il, rows j' = ig*4 + r. Store into tiled
  // plT[h][i>>4][jb*16+j'][i&15] as 4 scalar u16 stores.
  if (il < 12){
    size_t base = ((size_t)(il*32 + (i>>4))*512 + jb*16 + ig*4)*16 + (i&15);
    #pragma unroll
    for (int r=0;r<4;r++)
      plTbf[base + (size_t)r*16] = f2bf(acc[r]);
  }
}

// ================= K1: prep + pairbias =================
__global__ void k1_prep_pairbias(
    const float* __restrict__ s, const float* __restrict__ g_s, const float* __restrict__ b_s,
    const float* __restrict__ z,
    const float* __restrict__ Wq, const float* __restrict__ Wk, const float* __restrict__ Wv,
    const float* __restrict__ Wqp, const float* __restrict__ Wkp, const float* __restrict__ Wvp,
    const float* __restrict__ Wpb, const float* __restrict__ pw, const float* __restrict__ Wo,
    const float* __restrict__ g_z, const float* __restrict__ b_z,
    char* __restrict__ ws){
  unsigned short* snbf  = (unsigned short*)(ws + OFF_SNBF);
  unsigned short* plTbf = (unsigned short*)(ws + OFF_PLT);
  unsigned short* wcfrag= (unsigned short*)(ws + OFF_WCF);
  unsigned short* wofrag= (unsigned short*)(ws + OFF_WOF);
  float*          wbuf  = (float*)(ws + OFF_WBUF);
  const int bid = blockIdx.x, tid = threadIdx.x;
  const int w = tid>>6, lane = tid&63, il = lane&15, ig = lane>>4;

  if (bid < 192){
    int u = bid;
    if (u < 24){
      // wcfrag: k-chunk, coalesced along n
      int k = u*16 + (tid>>4), nloc = tid & 15;
      int kt = k>>5, kin = k&31;
      int fl = (kin>>3)*16 + nloc, r = kin&7;
      #pragma unroll 4
      for (int nt=0; nt<72; nt++){
        int n = nt*16 + nloc;
        float v;
        if      (n < 192) v = Wq [k*192 + n];
        else if (n < 384) v = Wk [k*192 + (n-192)];
        else if (n < 576) v = Wv [k*192 + (n-384)];
        else if (n < 720) v = Wqp[k*144 + (n-576)];
        else if (n < 864) v = Wkp[k*144 + (n-720)];
        else              v = Wvp[k*288 + (n-864)];
        wcfrag[((size_t)(nt*12+kt)*64 + fl)*8 + r] = f2bf(v);
      }
    } else if (u < 60){
      int k = (u-24)*16 + (tid>>4), nloc = tid & 15;
      int kt = k>>5, kin = k&31;
      int fl = (kin>>3)*16 + nloc, r = kin&7;
      #pragma unroll 4
      for (int nt=0; nt<24; nt++){
        int n = nt*16 + nloc;
        wofrag[((size_t)(nt*18+kt)*64 + fl)*8 + r] = f2bf(Wo[k*384 + n]);
      }
    } else if (u < 188){
      int l = (u-60)*4 + w;
      float v[6]; float sum=0.f, ss=0.f;
      #pragma unroll
      for (int k=0;k<6;k++){
        float x = s[l*384 + lane + 64*k];
        v[k]=x; sum += x; ss = fmaf(x,x,ss);
      }
      #pragma unroll
      for (int m=1;m<64;m<<=1){ sum += __shfl_xor(sum,m); ss += __shfl_xor(ss,m); }
      float mu = sum*(1.f/384.f);
      float var = ss*(1.f/384.f) - mu*mu;
      float rs = rsqrtf(var + 1e-5f);
      #pragma unroll
      for (int k=0;k<6;k++){
        int c = lane + 64*k;
        snbf[l*384 + c] = f2bf((v[k]-mu)*rs*g_s[c] + b_s[c]);
      }
    } else if (u == 188){
      if (tid < 12) wbuf[tid] = log1pf(expf(pw[tid]));
    }
    // prep blocks: 3 consecutive units each (units [0, 2304))
    bf16x8 gzb[4], bzb[4], wf[4];
    pb_frags(Wpb, g_z, b_z, il, ig, gzb, bzb, wf);
    int wl = bid*4 + w;
    #pragma unroll
    for (int e=0;e<3;e++)
      pb_unit(wl*3 + e, z, plTbf, il, ig, gzb, bzb, wf);
  } else {
    // other blocks: 4 consecutive units each from 2304, + 768 remainder units
    bf16x8 gzb[4], bzb[4], wf[4];
    pb_frags(Wpb, g_z, b_z, il, ig, gzb, bzb, wf);
    int wid = (bid-192)*4 + w;   // [0, 3328)
    int u0 = 2304 + wid*4;
    #pragma unroll
    for (int e=0;e<4;e++)
      pb_unit(u0 + e, z, plTbf, il, ig, gzb, bzb, wf);
    if (wid < 768)
      pb_unit(15616 + wid, z, plTbf, il, ig, gzb, bzb, wf);
  }
}

// ================= K2: projection GEMM + points (64 blocks x 256) =================
__global__ void k2_projpoints(const float* __restrict__ Rm, const float* __restrict__ tv,
    char* __restrict__ ws){
  unsigned short* snbf  = (unsigned short*)(ws + OFF_SNBF);
  float*          proj  = (float*)(ws + OFF_PROJ);
  float*          qpb   = (float*)(ws + OFF_QP);
  unsigned short* kfrag = (unsigned short*)(ws + OFF_KFRAG);
  unsigned short* vfrag = (unsigned short*)(ws + OFF_VFRAG);
  float*          kn2T  = (float*)(ws + OFF_KN2);
  unsigned short* wcfrag= (unsigned short*)(ws + OFF_WCF);
  const int bid = blockIdx.x, tid = threadIdx.x;
  const int w = tid>>6, lane = tid&63, il = lane&15, ig = lane>>4;
  int ib = bid >> 1, half = bid & 1;
  int i0 = ib*16;
  bf16x8 afr[12];
  #pragma unroll
  for (int kt=0;kt<12;kt++)
    afr[kt] = *(const bf16x8*)(snbf + (i0+il)*384 + kt*32 + ig*8);
  int w2 = half*4 + w;
  for (int nt = w2; nt < 72; nt += 8){
    f32x4 acc = {0.f,0.f,0.f,0.f};
    #pragma unroll
    for (int kt=0;kt<12;kt++){
      bf16x8 b = *(const bf16x8*)(wcfrag + ((size_t)(nt*12+kt)*64 + lane)*8);
      acc = MFMA16(afr[kt], b, acc);
    }
    #pragma unroll
    for (int r=0;r<4;r++)
      proj[(size_t)(i0 + ig*4 + r)*1152 + nt*16 + il] = acc[r];
  }
  __threadfence();
  __syncthreads();
  if (tid < 96){
    int rr = half*8 + tid/12, h = tid % 12;
    int l = i0 + rr;
    float Rl[9], tl[3];
    #pragma unroll
    for (int e=0;e<9;e++) Rl[e] = Rm[l*9+e];
    #pragma unroll
    for (int e=0;e<3;e++) tl[e] = tv[l*3+e];
    const float* prow = proj + (size_t)l*1152;
    #pragma unroll
    for (int p=0;p<4;p++){
      float lx = prow[576 + h*12 + p*3+0];
      float ly = prow[576 + h*12 + p*3+1];
      float lz = prow[576 + h*12 + p*3+2];
      qpb[((size_t)l*12+h)*12 + p*3+0] = Rl[0]*lx + Rl[1]*ly + Rl[2]*lz + tl[0];
      qpb[((size_t)l*12+h)*12 + p*3+1] = Rl[3]*lx + Rl[4]*ly + Rl[5]*lz + tl[1];
      qpb[((size_t)l*12+h)*12 + p*3+2] = Rl[6]*lx + Rl[7]*ly + Rl[8]*lz + tl[2];
    }
    float kp[12]; float kn2 = 0.f;
    #pragma unroll
    for (int p=0;p<4;p++){
      float lx = prow[720 + h*12 + p*3+0];
      float ly = prow[720 + h*12 + p*3+1];
      float lz = prow[720 + h*12 + p*3+2];
      float cx = Rl[0]*lx + Rl[1]*ly + Rl[2]*lz + tl[0];
      float cy = Rl[3]*lx + Rl[4]*ly + Rl[5]*lz + tl[1];
      float cz = Rl[6]*lx + Rl[7]*ly + Rl[8]*lz + tl[2];
      kp[p*3+0]=cx; kp[p*3+1]=cy; kp[p*3+2]=cz;
      kn2 += cx*cx + cy*cy + cz*cz;
    }
    kn2T[h*512 + l] = kn2;
    {
      int jt = l>>4, jl = l&15;
      #pragma unroll
      for (int k=0;k<32;k++){
        float f = (k<16) ? prow[192 + h*16 + k] : ((k<28) ? kp[k-16] : 0.f);
        kfrag[((size_t)(h*32+jt)*64 + 16*(k>>3) + jl)*8 + (k&7)] = f2bf(f);
      }
    }
    float vp[24];
    #pragma unroll
    for (int p=0;p<8;p++){
      float lx = prow[864 + h*24 + p*3+0];
      float ly = prow[864 + h*24 + p*3+1];
      float lz = prow[864 + h*24 + p*3+2];
      vp[p*3+0] = Rl[0]*lx + Rl[1]*ly + Rl[2]*lz + tl[0];
      vp[p*3+1] = Rl[3]*lx + Rl[4]*ly + Rl[5]*lz + tl[1];
      vp[p*3+2] = Rl[6]*lx + Rl[7]*ly + Rl[8]*lz + tl[2];
    }
    {
      int jc = l>>5, jin = l&31;
      int qq = (jin&15)>>2;
      int rv = (jin&3) + ((jin>>4)<<2);
      #pragma unroll
      for (int dd=0;dd<48;dd++){
        float f = (dd<16) ? prow[384 + h*16 + dd] : ((dd<40) ? vp[dd-16] : 0.f);
        int dt = dd>>4, d_ = dd&15;
        vfrag[((size_t)((h*16+jc)*3+dt)*64 + 16*qq + d_)*8 + rv] = f2bf(f);
      }
    }
  }
}

// ================= K3: attention (plT tile staged in LDS) =================
__global__ __launch_bounds__(512) void k3_attn(char* __restrict__ ws){
  float*          proj  = (float*)(ws + OFF_PROJ);
  float*          qpb   = (float*)(ws + OFF_QP);
  unsigned short* kfrag = (unsigned short*)(ws + OFF_KFRAG);
  unsigned short* vfrag = (unsigned short*)(ws + OFF_VFRAG);
  float*          kn2T  = (float*)(ws + OFF_KN2);
  unsigned short* plTbf = (unsigned short*)(ws + OFF_PLT);
  float*          obuf  = (float*)(ws + OFF_OBUF);
  float*          wbuf  = (float*)(ws + OFF_WBUF);

  __shared__ union {
    unsigned short ptile[512*20];                                      // 20480 B
    struct { float red[8][16]; float gsum[16]; float osum[8][64][13]; } a;  // 27200 B
  } sm;

  const int u = blockIdx.x, tid = threadIdx.x;
  const int w = tid>>6, lane = tid&63, il = lane&15, ig = lane>>4;
  const int h = u >> 5, ib = u & 31;
  const int i0 = ib*16;

  // ---- stage plT tile [512 j][16 i] -> LDS (row stride 20 u16) ----
  {
    const unsigned long long* s8 =
      (const unsigned long long*)(plTbf + (size_t)(h*32 + ib)*8192);
    int j = tid;
    unsigned long long a0 = s8[j*4+0], a1 = s8[j*4+1], a2 = s8[j*4+2], a3 = s8[j*4+3];
    unsigned long long* d = (unsigned long long*)&sm.ptile[j*20];
    d[0]=a0; d[1]=a1; d[2]=a2; d[3]=a3;
  }
  float wh = wbuf[h];
  float wneg = -0.5f*wh;
  bf16x8 qfrag;
  #pragma unroll
  for (int r=0;r<8;r++){
    int k = ig*8 + r; float f;
    if (k < 16)      f = proj[(size_t)(i0+il)*1152 + h*16 + k]*0.25f;
    else if (k < 28) f = qpb[((size_t)(i0+il)*12 + h)*12 + (k-16)]*wh;
    else             f = 0.f;
    qfrag[r] = (short)f2bf(f);
  }
  __syncthreads();   // ptile staged

  // ---- QK^T (S^T tiles), C0 from LDS ----
  int jt0 = w*4;
  f32x4 sv[4];
  const unsigned short* kbase = kfrag + (size_t)(h*32)*512;
  const float* kbn = kn2T + h*512;
  #pragma unroll
  for (int jj=0;jj<4;jj++){
    int jt = jt0+jj;
    bf16x8 kf = *(const bf16x8*)(kbase + (size_t)(jt*64 + lane)*8);
    f32x4 c0;
    #pragma unroll
    for (int r=0;r<4;r++){
      int j = jt*16 + ig*4 + r;
      c0[r] = bf2f(sm.ptile[j*20 + il]) + wneg*kbn[j];
    }
    sv[jj] = MFMA16(kf, qfrag, c0);
  }
  float mx = -3.0e38f;
  #pragma unroll
  for (int jj=0;jj<4;jj++)
    #pragma unroll
    for (int r=0;r<4;r++) mx = fmaxf(mx, sv[jj][r]);
  mx = fmaxf(mx, __shfl_xor(mx,16));
  mx = fmaxf(mx, __shfl_xor(mx,32));
  __syncthreads();   // all ptile reads done; union reuse is now safe
  if (lane < 16) sm.a.red[w][lane] = mx;
  __syncthreads();
  float gm = sm.a.red[0][il];
  #pragma unroll
  for (int ww=1;ww<8;ww++) gm = fmaxf(gm, sm.a.red[ww][il]);
  __syncthreads();
  float sum = 0.f;
  #pragma unroll
  for (int jj=0;jj<4;jj++)
    #pragma unroll
    for (int r=0;r<4;r++){ float p = __expf(sv[jj][r]-gm); sv[jj][r]=p; sum+=p; }
  sum += __shfl_xor(sum,16);
  sum += __shfl_xor(sum,32);
  if (lane < 16) sm.a.red[w][lane] = sum;
  __syncthreads();
  float gs = 0.f;
  #pragma unroll
  for (int ww=0;ww<8;ww++) gs += sm.a.red[ww][il];
  if (w == 0 && lane < 16) sm.a.gsum[lane] = gs;
  // ---- partial O^T = V^T @ P^T ----
  f32x4 o0={0.f,0.f,0.f,0.f}, o1=o0, o2=o0;
  const unsigned short* vbase = vfrag + (size_t)(h*16)*3*512;
  #pragma unroll
  for (int jcl=0;jcl<2;jcl++){
    int jc = w*2 + jcl;
    bf16x8 pfrag;
    #pragma unroll
    for (int r=0;r<8;r++) pfrag[r] = (short)f2bf(sv[2*jcl + (r>>2)][r&3]);
    bf16x8 v0 = *(const bf16x8*)(vbase + (size_t)((jc*3+0)*64 + lane)*8);
    bf16x8 v1 = *(const bf16x8*)(vbase + (size_t)((jc*3+1)*64 + lane)*8);
    bf16x8 v2 = *(const bf16x8*)(vbase + (size_t)((jc*3+2)*64 + lane)*8);
    o0 = MFMA16(v0, pfrag, o0);
    o1 = MFMA16(v1, pfrag, o1);
    o2 = MFMA16(v2, pfrag, o2);
  }
  #pragma unroll
  for (int r=0;r<4;r++){
    sm.a.osum[w][lane][r]   = o0[r];
    sm.a.osum[w][lane][4+r] = o1[r];
    sm.a.osum[w][lane][8+r] = o2[r];
  }
  __syncthreads();
  for (int idx = tid; idx < 640; idx += 512){
    int i = idx & 15, d = idx >> 4;
    int seg = d >> 4, dr = d & 15;
    int lx = ((dr>>2) << 4) + i;
    int c = seg*4 + (dr & 3);
    float v = 0.f;
    #pragma unroll
    for (int ww=0;ww<8;ww++) v += sm.a.osum[ww][lx][c];
    obuf[(size_t)(i0+i)*480 + h*40 + d] = v / sm.a.gsum[i];
  }
}

// ================= K4: cat + output GEMM (32 blocks x 256) =================
#define CATS 584   // row stride in u16; 584*2=1168 B = 73*16 -> 16B-aligned rows
__global__ __launch_bounds__(256) void k4_catout(
    const float* __restrict__ s, const float* __restrict__ Rm, const float* __restrict__ tv,
    const float* __restrict__ bo, float* __restrict__ out, char* __restrict__ ws){
  float*          obuf  = (float*)(ws + OFF_OBUF);
  unsigned short* wofrag= (unsigned short*)(ws + OFF_WOF);
  __shared__ unsigned short cat[16*CATS];
  const int u = blockIdx.x, tid = threadIdx.x;
  const int w = tid>>6, lane = tid&63, il = lane&15, ig = lane>>4;
  int i0 = u*16;
  if (tid < 192){
    int rr = tid/12, hh = tid - rr*12;
    int l = i0 + rr;
    float Rl[9], tl[3];
    #pragma unroll
    for (int e=0;e<9;e++) Rl[e] = Rm[l*9+e];
    #pragma unroll
    for (int e=0;e<3;e++) tl[e] = tv[l*3+e];
    const float* orow = obuf + (size_t)l*480 + hh*40;
    #pragma unroll
    for (int d=0;d<16;d++) cat[rr*CATS + hh*16 + d] = f2bf(orow[d]);
    #pragma unroll
    for (int p=0;p<8;p++){
      float oy0 = orow[16 + p*3 + 0] - tl[0];
      float oy1 = orow[16 + p*3 + 1] - tl[1];
      float oy2 = orow[16 + p*3 + 2] - tl[2];
      float px = Rl[0]*oy0 + Rl[3]*oy1 + Rl[6]*oy2;
      float py = Rl[1]*oy0 + Rl[4]*oy1 + Rl[7]*oy2;
      float pz = Rl[2]*oy0 + Rl[5]*oy1 + Rl[8]*oy2;
      int cb = 192 + (hh*8+p)*3;
      cat[rr*CATS + cb+0] = f2bf(px);
      cat[rr*CATS + cb+1] = f2bf(py);
      cat[rr*CATS + cb+2] = f2bf(pz);
      cat[rr*CATS + 480 + hh*8 + p] = f2bf(sqrtf(px*px + py*py + pz*pz + 1e-8f));
    }
  }
  __syncthreads();
  for (int nt = w; nt < 24; nt += 4){
    int n = nt*16 + il;
    f32x4 acc = {0.f,0.f,0.f,0.f};
    #pragma unroll
    for (int kt=0;kt<18;kt++){
      bf16x8 a = *(const bf16x8*)(&cat[il*CATS + kt*32 + ig*8]);
      bf16x8 b = *(const bf16x8*)(wofrag + ((size_t)(nt*18+kt)*64 + lane)*8);
      acc = MFMA16(a, b, acc);
    }
    float bv = bo[n];
    #pragma unroll
    for (int r=0;r<4;r++){
      int row = i0 + ig*4 + r;
      out[(size_t)row*384 + n] = s[(size_t)row*384 + n] + bv + acc[r];
    }
  }
}

extern "C" void kernel_launch(void* const* d_in, const int* in_sizes, int n_in,
                              void* d_out, int out_size, void* d_ws, size_t ws_size,
                              hipStream_t stream) {
  const float* s   = (const float*)d_in[0];
  const float* z   = (const float*)d_in[1];
  const float* R   = (const float*)d_in[2];
  const float* t   = (const float*)d_in[3];
  const float* g_s = (const float*)d_in[4];
  const float* b_s = (const float*)d_in[5];
  const float* g_z = (const float*)d_in[6];
  const float* b_z = (const float*)d_in[7];
  const float* Wq  = (const float*)d_in[8];
  const float* Wk  = (const float*)d_in[9];
  const float* Wv  = (const float*)d_in[10];
  const float* Wqp = (const float*)d_in[11];
  const float* Wkp = (const float*)d_in[12];
  const float* Wvp = (const float*)d_in[13];
  const float* Wpb = (const float*)d_in[14];
  const float* pw  = (const float*)d_in[15];
  const float* Wo  = (const float*)d_in[16];
  const float* bo  = (const float*)d_in[17];
  float* out = (float*)d_out;
  char* ws = (char*)d_ws;

  k1_prep_pairbias<<<1024, 256, 0, stream>>>(s, g_s, b_s, z,
      Wq, Wk, Wv, Wqp, Wkp, Wvp, Wpb, pw, Wo, g_z, b_z, ws);
  k2_projpoints<<<64, 256, 0, stream>>>(R, t, ws);
  k3_attn<<<384, 512, 0, stream>>>(ws);
  k4_catout<<<32, 256, 0, stream>>>(s, R, t, bo, out, ws);
}

// Round 8
// 107.974 us; speedup vs baseline: 1.1769x; 1.1769x over previous
//
#include <hip/hip_runtime.h>

typedef float f32x4 __attribute__((ext_vector_type(4)));
typedef unsigned u32x4 __attribute__((ext_vector_type(4)));
typedef short bf16x8 __attribute__((ext_vector_type(8)));

#define MFMA16(a,b,c) __builtin_amdgcn_mfma_f32_16x16x32_bf16((a),(b),(c),0,0,0)

__device__ __forceinline__ unsigned short f2bf(float f){
  unsigned int u = __builtin_bit_cast(unsigned int, f);
  u += 0x7FFFu + ((u>>16)&1u);
  return (unsigned short)(u>>16);
}
__device__ __forceinline__ float bf2f(unsigned short u){
  return __builtin_bit_cast(float, ((unsigned int)u)<<16);
}

// ---------------- ws layout (bytes) ----------------
#define OFF_SNBF  0u          // 512*384*2      = 393216
#define OFF_PROJ  393216u     // 512*1152*4     = 2359296
#define OFF_QP    2752512u    // 512*144*4      = 294912
#define OFF_KFRAG 3047424u    // 12*32*64*8*2   = 393216
#define OFF_VFRAG 3440640u    // 12*16*3*64*8*2 = 589824
#define OFF_KN2   4030464u    // 12*512*4       = 24576
#define OFF_PLT   4055040u    // 12*32*512*16*2 = 6291456 (bf16, tiled [h][ib][j][16])
#define OFF_OBUF  10346496u   // 512*480*4      = 983040
#define OFF_WCF   11329536u   // 72*12*64*8*2   = 884736
#define OFF_WOF   12214272u   // 24*18*64*8*2   = 442368
#define OFF_WBUF  12656640u   // 12*4 (pad 256)

// ---- pairbias helpers ----
__device__ __forceinline__ void pb_frags(const float* __restrict__ Wpb,
    const float* __restrict__ g_z, const float* __restrict__ b_z,
    int il, int ig, bf16x8* gzb, bf16x8* bzb, bf16x8* wf){
  #pragma unroll
  for (int c=0;c<4;c++){
    #pragma unroll
    for (int r=0;r<8;r++){
      int cc = c*32 + ig*8 + r;
      gzb[c][r] = (short)f2bf(g_z[cc]);
      bzb[c][r] = (short)f2bf(b_z[cc]);
      wf[c][r]  = (il<12) ? (short)f2bf(Wpb[cc*12 + il]) : (short)0;
    }
  }
}

// one unit: LN + bias-GEMM for 16 j-rows of s-row i (contiguous 8 KB of z).
// Result C[j'][h] written to LDS cmat[h][j'][iloc] (row stride 18 u16).
__device__ __forceinline__ void pb_unit_lds(int i, int jb, int iloc,
    unsigned short* __restrict__ cmat, const float* __restrict__ z,
    int il, int ig, const bf16x8* gzb, const bf16x8* bzb, const bf16x8* wf){
  const float* zr = z + ((size_t)i*512 + jb*16)*128 + il*128;
  f32x4 zv[8];
  #pragma unroll
  for (int c=0;c<4;c++){
    zv[2*c]   = *(const f32x4*)(zr + c*32 + ig*8);
    zv[2*c+1] = *(const f32x4*)(zr + c*32 + ig*8 + 4);
  }
  float sum=0.f, ss=0.f;
  #pragma unroll
  for (int m=0;m<8;m++)
    #pragma unroll
    for (int e=0;e<4;e++){ float x = zv[m][e]; sum += x; ss = fmaf(x,x,ss); }
  sum += __shfl_xor(sum,16); sum += __shfl_xor(sum,32);
  ss  += __shfl_xor(ss,16);  ss  += __shfl_xor(ss,32);
  float mu  = sum*(1.f/128.f);
  float var = ss*(1.f/128.f) - mu*mu;
  float rs  = rsqrtf(var + 1e-5f);
  f32x4 acc = {0.f,0.f,0.f,0.f};
  #pragma unroll
  for (int c=0;c<4;c++){
    bf16x8 zf;
    #pragma unroll
    for (int r=0;r<8;r++){
      float xv = (r<4)? zv[2*c][r&3] : zv[2*c+1][r&3];
      float gv = bf2f((unsigned short)gzb[c][r]);
      float bv = bf2f((unsigned short)bzb[c][r]);
      zf[r] = (short)f2bf((xv-mu)*(rs*gv) + bv);
    }
    acc = MFMA16(zf, wf[c], acc);
  }
  // C col = h = il, rows j' = ig*4 + r
  if (il < 12){
    #pragma unroll
    for (int r=0;r<4;r++)
      cmat[(il*16 + ig*4 + r)*18 + iloc] = f2bf(acc[r]);
  }
}

// ================= K1: prep + pairbias (block = one 16x16 (ib,jb) tile) =================
__global__ __launch_bounds__(256) void k1_prep_pairbias(
    const float* __restrict__ s, const float* __restrict__ g_s, const float* __restrict__ b_s,
    const float* __restrict__ z,
    const float* __restrict__ Wq, const float* __restrict__ Wk, const float* __restrict__ Wv,
    const float* __restrict__ Wqp, const float* __restrict__ Wkp, const float* __restrict__ Wvp,
    const float* __restrict__ Wpb, const float* __restrict__ pw, const float* __restrict__ Wo,
    const float* __restrict__ g_z, const float* __restrict__ b_z,
    char* __restrict__ ws){
  unsigned short* snbf  = (unsigned short*)(ws + OFF_SNBF);
  unsigned short* plTbf = (unsigned short*)(ws + OFF_PLT);
  unsigned short* wcfrag= (unsigned short*)(ws + OFF_WCF);
  unsigned short* wofrag= (unsigned short*)(ws + OFF_WOF);
  float*          wbuf  = (float*)(ws + OFF_WBUF);
  const int bid = blockIdx.x, tid = threadIdx.x;
  const int w = tid>>6, lane = tid&63, il = lane&15, ig = lane>>4;

  __shared__ unsigned cmat32[12*16*9];   // [h][j][9 u32] = [h][j][18 u16] (16 + 2 pad)

  if (bid < 192){
    int u = bid;
    if (u < 24){
      // wcfrag: k-chunk, coalesced along n
      int k = u*16 + (tid>>4), nloc = tid & 15;
      int kt = k>>5, kin = k&31;
      int fl = (kin>>3)*16 + nloc, r = kin&7;
      #pragma unroll 4
      for (int nt=0; nt<72; nt++){
        int n = nt*16 + nloc;
        float v;
        if      (n < 192) v = Wq [k*192 + n];
        else if (n < 384) v = Wk [k*192 + (n-192)];
        else if (n < 576) v = Wv [k*192 + (n-384)];
        else if (n < 720) v = Wqp[k*144 + (n-576)];
        else if (n < 864) v = Wkp[k*144 + (n-720)];
        else              v = Wvp[k*288 + (n-864)];
        wcfrag[((size_t)(nt*12+kt)*64 + fl)*8 + r] = f2bf(v);
      }
    } else if (u < 60){
      int k = (u-24)*16 + (tid>>4), nloc = tid & 15;
      int kt = k>>5, kin = k&31;
      int fl = (kin>>3)*16 + nloc, r = kin&7;
      #pragma unroll 4
      for (int nt=0; nt<24; nt++){
        int n = nt*16 + nloc;
        wofrag[((size_t)(nt*18+kt)*64 + fl)*8 + r] = f2bf(Wo[k*384 + n]);
      }
    } else if (u < 188){
      int l = (u-60)*4 + w;
      float v[6]; float sum=0.f, ss=0.f;
      #pragma unroll
      for (int k=0;k<6;k++){
        float x = s[l*384 + lane + 64*k];
        v[k]=x; sum += x; ss = fmaf(x,x,ss);
      }
      #pragma unroll
      for (int m=1;m<64;m<<=1){ sum += __shfl_xor(sum,m); ss += __shfl_xor(ss,m); }
      float mu = sum*(1.f/384.f);
      float var = ss*(1.f/384.f) - mu*mu;
      float rs = rsqrtf(var + 1e-5f);
      #pragma unroll
      for (int k=0;k<6;k++){
        int c = lane + 64*k;
        snbf[l*384 + c] = f2bf((v[k]-mu)*rs*g_s[c] + b_s[c]);
      }
    } else if (u == 188){
      if (tid < 12) wbuf[tid] = log1pf(expf(pw[tid]));
    }
  }

  // ---- every block: one (ib, jb) pairbias tile ----
  bf16x8 gzb[4], bzb[4], wf[4];
  pb_frags(Wpb, g_z, b_z, il, ig, gzb, bzb, wf);
  int ib = bid >> 5, jb = bid & 31;
  unsigned short* cmat = (unsigned short*)cmat32;
  #pragma unroll
  for (int e=0;e<4;e++)
    pb_unit_lds(ib*16 + w*4 + e, jb, w*4 + e, cmat, z, il, ig, gzb, bzb, wf);
  __syncthreads();
  if (tid < 192){
    int h = tid >> 4, j = tid & 15;
    u32x4 q0, q1;
    #pragma unroll
    for (int e=0;e<4;e++) q0[e] = cmat32[(h*16 + j)*9 + e];
    #pragma unroll
    for (int e=0;e<4;e++) q1[e] = cmat32[(h*16 + j)*9 + 4 + e];
    unsigned* dst = (unsigned*)(plTbf + ((size_t)(h*32 + ib)*512 + jb*16 + j)*16);
    *(u32x4*)dst       = q0;
    *((u32x4*)dst + 1) = q1;
  }
}

// ================= K2: projection GEMM + points (64 blocks x 256) =================
__global__ void k2_projpoints(const float* __restrict__ Rm, const float* __restrict__ tv,
    char* __restrict__ ws){
  unsigned short* snbf  = (unsigned short*)(ws + OFF_SNBF);
  float*          proj  = (float*)(ws + OFF_PROJ);
  float*          qpb   = (float*)(ws + OFF_QP);
  unsigned short* kfrag = (unsigned short*)(ws + OFF_KFRAG);
  unsigned short* vfrag = (unsigned short*)(ws + OFF_VFRAG);
  float*          kn2T  = (float*)(ws + OFF_KN2);
  unsigned short* wcfrag= (unsigned short*)(ws + OFF_WCF);
  const int bid = blockIdx.x, tid = threadIdx.x;
  const int w = tid>>6, lane = tid&63, il = lane&15, ig = lane>>4;
  int ib = bid >> 1, half = bid & 1;
  int i0 = ib*16;
  bf16x8 afr[12];
  #pragma unroll
  for (int kt=0;kt<12;kt++)
    afr[kt] = *(const bf16x8*)(snbf + (i0+il)*384 + kt*32 + ig*8);
  int w2 = half*4 + w;
  for (int nt = w2; nt < 72; nt += 8){
    f32x4 acc = {0.f,0.f,0.f,0.f};
    #pragma unroll
    for (int kt=0;kt<12;kt++){
      bf16x8 b = *(const bf16x8*)(wcfrag + ((size_t)(nt*12+kt)*64 + lane)*8);
      acc = MFMA16(afr[kt], b, acc);
    }
    #pragma unroll
    for (int r=0;r<4;r++)
      proj[(size_t)(i0 + ig*4 + r)*1152 + nt*16 + il] = acc[r];
  }
  __threadfence();
  __syncthreads();
  if (tid < 96){
    int rr = half*8 + tid/12, h = tid % 12;
    int l = i0 + rr;
    float Rl[9], tl[3];
    #pragma unroll
    for (int e=0;e<9;e++) Rl[e] = Rm[l*9+e];
    #pragma unroll
    for (int e=0;e<3;e++) tl[e] = tv[l*3+e];
    const float* prow = proj + (size_t)l*1152;
    #pragma unroll
    for (int p=0;p<4;p++){
      float lx = prow[576 + h*12 + p*3+0];
      float ly = prow[576 + h*12 + p*3+1];
      float lz = prow[576 + h*12 + p*3+2];
      qpb[((size_t)l*12+h)*12 + p*3+0] = Rl[0]*lx + Rl[1]*ly + Rl[2]*lz + tl[0];
      qpb[((size_t)l*12+h)*12 + p*3+1] = Rl[3]*lx + Rl[4]*ly + Rl[5]*lz + tl[1];
      qpb[((size_t)l*12+h)*12 + p*3+2] = Rl[6]*lx + Rl[7]*ly + Rl[8]*lz + tl[2];
    }
    float kp[12]; float kn2 = 0.f;
    #pragma unroll
    for (int p=0;p<4;p++){
      float lx = prow[720 + h*12 + p*3+0];
      float ly = prow[720 + h*12 + p*3+1];
      float lz = prow[720 + h*12 + p*3+2];
      float cx = Rl[0]*lx + Rl[1]*ly + Rl[2]*lz + tl[0];
      float cy = Rl[3]*lx + Rl[4]*ly + Rl[5]*lz + tl[1];
      float cz = Rl[6]*lx + Rl[7]*ly + Rl[8]*lz + tl[2];
      kp[p*3+0]=cx; kp[p*3+1]=cy; kp[p*3+2]=cz;
      kn2 += cx*cx + cy*cy + cz*cz;
    }
    kn2T[h*512 + l] = kn2;
    {
      int jt = l>>4, jl = l&15;
      #pragma unroll
      for (int k=0;k<32;k++){
        float f = (k<16) ? prow[192 + h*16 + k] : ((k<28) ? kp[k-16] : 0.f);
        kfrag[((size_t)(h*32+jt)*64 + 16*(k>>3) + jl)*8 + (k&7)] = f2bf(f);
      }
    }
    float vp[24];
    #pragma unroll
    for (int p=0;p<8;p++){
      float lx = prow[864 + h*24 + p*3+0];
      float ly = prow[864 + h*24 + p*3+1];
      float lz = prow[864 + h*24 + p*3+2];
      vp[p*3+0] = Rl[0]*lx + Rl[1]*ly + Rl[2]*lz + tl[0];
      vp[p*3+1] = Rl[3]*lx + Rl[4]*ly + Rl[5]*lz + tl[1];
      vp[p*3+2] = Rl[6]*lx + Rl[7]*ly + Rl[8]*lz + tl[2];
    }
    {
      int jc = l>>5, jin = l&31;
      int qq = (jin&15)>>2;
      int rv = (jin&3) + ((jin>>4)<<2);
      #pragma unroll
      for (int dd=0;dd<48;dd++){
        float f = (dd<16) ? prow[384 + h*16 + dd] : ((dd<40) ? vp[dd-16] : 0.f);
        int dt = dd>>4, d_ = dd&15;
        vfrag[((size_t)((h*16+jc)*3+dt)*64 + 16*qq + d_)*8 + rv] = f2bf(f);
      }
    }
  }
}

// ================= K3: attention (plT tile staged in LDS) =================
__global__ __launch_bounds__(512) void k3_attn(char* __restrict__ ws){
  float*          proj  = (float*)(ws + OFF_PROJ);
  float*          qpb   = (float*)(ws + OFF_QP);
  unsigned short* kfrag = (unsigned short*)(ws + OFF_KFRAG);
  unsigned short* vfrag = (unsigned short*)(ws + OFF_VFRAG);
  float*          kn2T  = (float*)(ws + OFF_KN2);
  unsigned short* plTbf = (unsigned short*)(ws + OFF_PLT);
  float*          obuf  = (float*)(ws + OFF_OBUF);
  float*          wbuf  = (float*)(ws + OFF_WBUF);

  __shared__ union {
    unsigned short ptile[512*20];                                      // 20480 B
    struct { float red[8][16]; float gsum[16]; float osum[8][64][13]; } a;  // 27200 B
  } sm;

  const int u = blockIdx.x, tid = threadIdx.x;
  const int w = tid>>6, lane = tid&63, il = lane&15, ig = lane>>4;
  const int h = u >> 5, ib = u & 31;
  const int i0 = ib*16;

  // ---- stage plT tile [512 j][16 i] -> LDS (row stride 20 u16) ----
  {
    const unsigned long long* s8 =
      (const unsigned long long*)(plTbf + (size_t)(h*32 + ib)*8192);
    int j = tid;
    unsigned long long a0 = s8[j*4+0], a1 = s8[j*4+1], a2 = s8[j*4+2], a3 = s8[j*4+3];
    unsigned long long* d = (unsigned long long*)&sm.ptile[j*20];
    d[0]=a0; d[1]=a1; d[2]=a2; d[3]=a3;
  }
  float wh = wbuf[h];
  float wneg = -0.5f*wh;
  bf16x8 qfrag;
  #pragma unroll
  for (int r=0;r<8;r++){
    int k = ig*8 + r; float f;
    if (k < 16)      f = proj[(size_t)(i0+il)*1152 + h*16 + k]*0.25f;
    else if (k < 28) f = qpb[((size_t)(i0+il)*12 + h)*12 + (k-16)]*wh;
    else             f = 0.f;
    qfrag[r] = (short)f2bf(f);
  }
  __syncthreads();   // ptile staged

  // ---- QK^T (S^T tiles), C0 from LDS ----
  int jt0 = w*4;
  f32x4 sv[4];
  const unsigned short* kbase = kfrag + (size_t)(h*32)*512;
  const float* kbn = kn2T + h*512;
  #pragma unroll
  for (int jj=0;jj<4;jj++){
    int jt = jt0+jj;
    bf16x8 kf = *(const bf16x8*)(kbase + (size_t)(jt*64 + lane)*8);
    f32x4 c0;
    #pragma unroll
    for (int r=0;r<4;r++){
      int j = jt*16 + ig*4 + r;
      c0[r] = bf2f(sm.ptile[j*20 + il]) + wneg*kbn[j];
    }
    sv[jj] = MFMA16(kf, qfrag, c0);
  }
  float mx = -3.0e38f;
  #pragma unroll
  for (int jj=0;jj<4;jj++)
    #pragma unroll
    for (int r=0;r<4;r++) mx = fmaxf(mx, sv[jj][r]);
  mx = fmaxf(mx, __shfl_xor(mx,16));
  mx = fmaxf(mx, __shfl_xor(mx,32));
  __syncthreads();   // all ptile reads done; union reuse is now safe
  if (lane < 16) sm.a.red[w][lane] = mx;
  __syncthreads();
  float gm = sm.a.red[0][il];
  #pragma unroll
  for (int ww=1;ww<8;ww++) gm = fmaxf(gm, sm.a.red[ww][il]);
  __syncthreads();
  float sum = 0.f;
  #pragma unroll
  for (int jj=0;jj<4;jj++)
    #pragma unroll
    for (int r=0;r<4;r++){ float p = __expf(sv[jj][r]-gm); sv[jj][r]=p; sum+=p; }
  sum += __shfl_xor(sum,16);
  sum += __shfl_xor(sum,32);
  if (lane < 16) sm.a.red[w][lane] = sum;
  __syncthreads();
  float gs = 0.f;
  #pragma unroll
  for (int ww=0;ww<8;ww++) gs += sm.a.red[ww][il];
  if (w == 0 && lane < 16) sm.a.gsum[lane] = gs;
  // ---- partial O^T = V^T @ P^T ----
  f32x4 o0={0.f,0.f,0.f,0.f}, o1=o0, o2=o0;
  const unsigned short* vbase = vfrag + (size_t)(h*16)*3*512;
  #pragma unroll
  for (int jcl=0;jcl<2;jcl++){
    int jc = w*2 + jcl;
    bf16x8 pfrag;
    #pragma unroll
    for (int r=0;r<8;r++) pfrag[r] = (short)f2bf(sv[2*jcl + (r>>2)][r&3]);
    bf16x8 v0 = *(const bf16x8*)(vbase + (size_t)((jc*3+0)*64 + lane)*8);
    bf16x8 v1 = *(const bf16x8*)(vbase + (size_t)((jc*3+1)*64 + lane)*8);
    bf16x8 v2 = *(const bf16x8*)(vbase + (size_t)((jc*3+2)*64 + lane)*8);
    o0 = MFMA16(v0, pfrag, o0);
    o1 = MFMA16(v1, pfrag, o1);
    o2 = MFMA16(v2, pfrag, o2);
  }
  #pragma unroll
  for (int r=0;r<4;r++){
    sm.a.osum[w][lane][r]   = o0[r];
    sm.a.osum[w][lane][4+r] = o1[r];
    sm.a.osum[w][lane][8+r] = o2[r];
  }
  __syncthreads();
  for (int idx = tid; idx < 640; idx += 512){
    int i = idx & 15, d = idx >> 4;
    int seg = d >> 4, dr = d & 15;
    int lx = ((dr>>2) << 4) + i;
    int c = seg*4 + (dr & 3);
    float v = 0.f;
    #pragma unroll
    for (int ww=0;ww<8;ww++) v += sm.a.osum[ww][lx][c];
    obuf[(size_t)(i0+i)*480 + h*40 + d] = v / sm.a.gsum[i];
  }
}

// ================= K4: cat + output GEMM (32 blocks x 256) =================
#define CATS 584   // row stride in u16; 584*2=1168 B = 73*16 -> 16B-aligned rows
__global__ __launch_bounds__(256) void k4_catout(
    const float* __restrict__ s, const float* __restrict__ Rm, const float* __restrict__ tv,
    const float* __restrict__ bo, float* __restrict__ out, char* __restrict__ ws){
  float*          obuf  = (float*)(ws + OFF_OBUF);
  unsigned short* wofrag= (unsigned short*)(ws + OFF_WOF);
  __shared__ unsigned short cat[16*CATS];
  const int u = blockIdx.x, tid = threadIdx.x;
  const int w = tid>>6, lane = tid&63, il = lane&15, ig = lane>>4;
  int i0 = u*16;
  if (tid < 192){
    int rr = tid/12, hh = tid - rr*12;
    int l = i0 + rr;
    float Rl[9], tl[3];
    #pragma unroll
    for (int e=0;e<9;e++) Rl[e] = Rm[l*9+e];
    #pragma unroll
    for (int e=0;e<3;e++) tl[e] = tv[l*3+e];
    const float* orow = obuf + (size_t)l*480 + hh*40;
    #pragma unroll
    for (int d=0;d<16;d++) cat[rr*CATS + hh*16 + d] = f2bf(orow[d]);
    #pragma unroll
    for (int p=0;p<8;p++){
      float oy0 = orow[16 + p*3 + 0] - tl[0];
      float oy1 = orow[16 + p*3 + 1] - tl[1];
      float oy2 = orow[16 + p*3 + 2] - tl[2];
      float px = Rl[0]*oy0 + Rl[3]*oy1 + Rl[6]*oy2;
      float py = Rl[1]*oy0 + Rl[4]*oy1 + Rl[7]*oy2;
      float pz = Rl[2]*oy0 + Rl[5]*oy1 + Rl[8]*oy2;
      int cb = 192 + (hh*8+p)*3;
      cat[rr*CATS + cb+0] = f2bf(px);
      cat[rr*CATS + cb+1] = f2bf(py);
      cat[rr*CATS + cb+2] = f2bf(pz);
      cat[rr*CATS + 480 + hh*8 + p] = f2bf(sqrtf(px*px + py*py + pz*pz + 1e-8f));
    }
  }
  __syncthreads();
  for (int nt = w; nt < 24; nt += 4){
    int n = nt*16 + il;
    f32x4 acc = {0.f,0.f,0.f,0.f};
    #pragma unroll
    for (int kt=0;kt<18;kt++){
      bf16x8 a = *(const bf16x8*)(&cat[il*CATS + kt*32 + ig*8]);
      bf16x8 b = *(const bf16x8*)(wofrag + ((size_t)(nt*18+kt)*64 + lane)*8);
      acc = MFMA16(a, b, acc);
    }
    float bv = bo[n];
    #pragma unroll
    for (int r=0;r<4;r++){
      int row = i0 + ig*4 + r;
      out[(size_t)row*384 + n] = s[(size_t)row*384 + n] + bv + acc[r];
    }
  }
}

extern "C" void kernel_launch(void* const* d_in, const int* in_sizes, int n_in,
                              void* d_out, int out_size, void* d_ws, size_t ws_size,
                              hipStream_t stream) {
  const float* s   = (const float*)d_in[0];
  const float* z   = (const float*)d_in[1];
  const float* R   = (const float*)d_in[2];
  const float* t   = (const float*)d_in[3];
  const float* g_s = (const float*)d_in[4];
  const float* b_s = (const float*)d_in[5];
  const float* g_z = (const float*)d_in[6];
  const float* b_z = (const float*)d_in[7];
  const float* Wq  = (const float*)d_in[8];
  const float* Wk  = (const float*)d_in[9];
  const float* Wv  = (const float*)d_in[10];
  const float* Wqp = (const float*)d_in[11];
  const float* Wkp = (const float*)d_in[12];
  const float* Wvp = (const float*)d_in[13];
  const float* Wpb = (const float*)d_in[14];
  const float* pw  = (const float*)d_in[15];
  const float* Wo  = (const float*)d_in[16];
  const float* bo  = (const float*)d_in[17];
  float* out = (float*)d_out;
  char* ws = (char*)d_ws;

  k1_prep_pairbias<<<1024, 256, 0, stream>>>(s, g_s, b_s, z,
      Wq, Wk, Wv, Wqp, Wkp, Wvp, Wpb, pw, Wo, g_z, b_z, ws);
  k2_projpoints<<<64, 256, 0, stream>>>(R, t, ws);
  k3_attn<<<384, 512, 0, stream>>>(ws);
  k4_catout<<<32, 256, 0, stream>>>(s, R, t, bo, out, ws);
}

// Round 10
// 102.295 us; speedup vs baseline: 1.2422x; 1.0555x over previous
//
#include <hip/hip_runtime.h>

typedef float f32x4 __attribute__((ext_vector_type(4)));
typedef unsigned u32x4 __attribute__((ext_vector_type(4)));
typedef short bf16x8 __attribute__((ext_vector_type(8)));

#define MFMA16(a,b,c) __builtin_amdgcn_mfma_f32_16x16x32_bf16((a),(b),(c),0,0,0)

__device__ __forceinline__ unsigned short f2bf(float f){
  unsigned int u = __builtin_bit_cast(unsigned int, f);
  u += 0x7FFFu + ((u>>16)&1u);
  return (unsigned short)(u>>16);
}
__device__ __forceinline__ float bf2f(unsigned short u){
  return __builtin_bit_cast(float, ((unsigned int)u)<<16);
}

// ---------------- ws layout (bytes) ----------------
#define OFF_SNBF  0u          // 512*384*2      = 393216
#define OFF_PROJ  393216u     // 512*1152*4     = 2359296
#define OFF_QP    2752512u    // 512*144*4      = 294912
#define OFF_KFRAG 3047424u    // 12*32*64*8*2   = 393216
#define OFF_VFRAG 3440640u    // 12*16*3*64*8*2 = 589824
#define OFF_KN2   4030464u    // 12*512*4       = 24576
#define OFF_PLT   4055040u    // 12*32*512*16*2 = 6291456 (bf16, tiled [h][ib][j][16])
#define OFF_OBUF  10346496u   // 512*480*4      = 983040
#define OFF_WCF   11329536u   // 72*12*64*8*2   = 884736
#define OFF_WOF   12214272u   // 24*18*64*8*2   = 442368
#define OFF_WBUF  12656640u   // 12*4 (pad 256)

// ================= K1: prep + pairbias (block = one 16x16 (ib,jb) tile) =================
// Pairbias unit = (i, jb): LN over 16 j-rows of z[i] (8 KB contiguous) + @Wpb via MFMA.
// Register-lean: wf/gz/bz live in LDS; two named z-tiles (zA/zB) give a 2-deep pipeline.

#define PB_LOAD(ZV, E) { \
  const float* zr_ = ztile + (size_t)(w*4+(E))*65536; \
  _Pragma("unroll") \
  for (int c=0;c<4;c++){ \
    ZV##v[2*c]   = *(const f32x4*)(zr_ + c*32 + ig*8); \
    ZV##v[2*c+1] = *(const f32x4*)(zr_ + c*32 + ig*8 + 4); \
  } }

#define PB_PROC(ZV, E) { \
  float sum=0.f, ss=0.f; \
  _Pragma("unroll") \
  for (int m=0;m<8;m++) \
    _Pragma("unroll") \
    for (int e2=0;e2<4;e2++){ float x = ZV##v[m][e2]; sum += x; ss = fmaf(x,x,ss); } \
  sum += __shfl_xor(sum,16); sum += __shfl_xor(sum,32); \
  ss  += __shfl_xor(ss,16);  ss  += __shfl_xor(ss,32); \
  float mu  = sum*(1.f/128.f); \
  float var = ss*(1.f/128.f) - mu*mu; \
  float rs  = rsqrtf(var + 1e-5f); \
  f32x4 acc = {0.f,0.f,0.f,0.f}; \
  _Pragma("unroll") \
  for (int c=0;c<4;c++){ \
    f32x4 ga = *(const f32x4*)&gz_l[c][ig*8]; \
    f32x4 gb = *(const f32x4*)&gz_l[c][ig*8+4]; \
    f32x4 ba = *(const f32x4*)&bz_l[c][ig*8]; \
    f32x4 bb = *(const f32x4*)&bz_l[c][ig*8+4]; \
    bf16x8 wfc = *(const bf16x8*)&wf_l[c][lane][0]; \
    bf16x8 zf; \
    _Pragma("unroll") \
    for (int r=0;r<8;r++){ \
      float xv = (r<4)? ZV##v[2*c][r&3] : ZV##v[2*c+1][r&3]; \
      float gv = (r<4)? ga[r&3] : gb[r&3]; \
      float bv = (r<4)? ba[r&3] : bb[r&3]; \
      zf[r] = (short)f2bf((xv-mu)*(rs*gv) + bv); \
    } \
    acc = MFMA16(zf, wfc, acc); \
  } \
  if (il < 12){ \
    _Pragma("unroll") \
    for (int r=0;r<4;r++) \
      cmat[(il*16 + ig*4 + r)*18 + (w*4+(E))] = f2bf(acc[r]); \
  } }

__global__ __launch_bounds__(256) void k1_prep_pairbias(
    const float* __restrict__ s, const float* __restrict__ g_s, const float* __restrict__ b_s,
    const float* __restrict__ z,
    const float* __restrict__ Wq, const float* __restrict__ Wk, const float* __restrict__ Wv,
    const float* __restrict__ Wqp, const float* __restrict__ Wkp, const float* __restrict__ Wvp,
    const float* __restrict__ Wpb, const float* __restrict__ pw, const float* __restrict__ Wo,
    const float* __restrict__ g_z, const float* __restrict__ b_z,
    char* __restrict__ ws){
  unsigned short* snbf  = (unsigned short*)(ws + OFF_SNBF);
  unsigned short* plTbf = (unsigned short*)(ws + OFF_PLT);
  unsigned short* wcfrag= (unsigned short*)(ws + OFF_WCF);
  unsigned short* wofrag= (unsigned short*)(ws + OFF_WOF);
  float*          wbuf  = (float*)(ws + OFF_WBUF);
  const int bid = blockIdx.x, tid = threadIdx.x;
  const int w = tid>>6, lane = tid&63, il = lane&15, ig = lane>>4;

  __shared__ unsigned short wf_l[4][64][8];   // 4096 B: Wpb bf16 frag per (c, lane)
  __shared__ float gz_l[4][32];               // 512 B
  __shared__ float bz_l[4][32];               // 512 B
  __shared__ unsigned cmat32[12*16*9];        // 6912 B: [h][j][18 u16] (16 + 2 pad)
  unsigned short* cmat = (unsigned short*)cmat32;

  // ---- LDS constant setup ----
  {
    int c = tid >> 6, ln = tid & 63;
    int ili = ln & 15, igi = ln >> 4;
    #pragma unroll
    for (int r=0;r<8;r++){
      int cc = c*32 + igi*8 + r;
      wf_l[c][ln][r] = (ili<12) ? f2bf(Wpb[cc*12 + ili]) : (unsigned short)0;
    }
    if (tid < 128){
      int cc2 = tid >> 5, k2 = tid & 31;
      gz_l[cc2][k2] = g_z[cc2*32 + k2];
      bz_l[cc2][k2] = b_z[cc2*32 + k2];
    }
  }

  if (bid < 192){
    int u = bid;
    if (u < 24){
      // wcfrag: k-chunk, coalesced along n
      int k = u*16 + (tid>>4), nloc = tid & 15;
      int kt = k>>5, kin = k&31;
      int fl = (kin>>3)*16 + nloc, r = kin&7;
      #pragma unroll 4
      for (int nt=0; nt<72; nt++){
        int n = nt*16 + nloc;
        float v;
        if      (n < 192) v = Wq [k*192 + n];
        else if (n < 384) v = Wk [k*192 + (n-192)];
        else if (n < 576) v = Wv [k*192 + (n-384)];
        else if (n < 720) v = Wqp[k*144 + (n-576)];
        else if (n < 864) v = Wkp[k*144 + (n-720)];
        else              v = Wvp[k*288 + (n-864)];
        wcfrag[((size_t)(nt*12+kt)*64 + fl)*8 + r] = f2bf(v);
      }
    } else if (u < 60){
      int k = (u-24)*16 + (tid>>4), nloc = tid & 15;
      int kt = k>>5, kin = k&31;
      int fl = (kin>>3)*16 + nloc, r = kin&7;
      #pragma unroll 4
      for (int nt=0; nt<24; nt++){
        int n = nt*16 + nloc;
        wofrag[((size_t)(nt*18+kt)*64 + fl)*8 + r] = f2bf(Wo[k*384 + n]);
      }
    } else if (u < 188){
      int l = (u-60)*4 + w;
      float v[6]; float sum=0.f, ss=0.f;
      #pragma unroll
      for (int k=0;k<6;k++){
        float x = s[l*384 + lane + 64*k];
        v[k]=x; sum += x; ss = fmaf(x,x,ss);
      }
      #pragma unroll
      for (int m=1;m<64;m<<=1){ sum += __shfl_xor(sum,m); ss += __shfl_xor(ss,m); }
      float mu = sum*(1.f/384.f);
      float var = ss*(1.f/384.f) - mu*mu;
      float rs = rsqrtf(var + 1e-5f);
      #pragma unroll
      for (int k=0;k<6;k++){
        int c = lane + 64*k;
        snbf[l*384 + c] = f2bf((v[k]-mu)*rs*g_s[c] + b_s[c]);
      }
    } else if (u == 188){
      if (tid < 12) wbuf[tid] = log1pf(expf(pw[tid]));
    }
  }
  __syncthreads();   // LDS constants ready

  // ---- pairbias tile (ib, jb): 4 units/wave, 2-deep pipelined ----
  int ib = bid >> 5, jb = bid & 31;
  const float* ztile = z + (((size_t)ib*16)*512 + jb*16)*128 + il*128;
  f32x4 zAv[8], zBv[8];
  PB_LOAD(zA, 0)
  PB_LOAD(zB, 1)
  PB_PROC(zA, 0)
  PB_LOAD(zA, 2)
  PB_PROC(zB, 1)
  PB_LOAD(zB, 3)
  PB_PROC(zA, 2)
  PB_PROC(zB, 3)
  __syncthreads();
  if (tid < 192){
    int h = tid >> 4, j = tid & 15;
    u32x4 q0, q1;
    #pragma unroll
    for (int e=0;e<4;e++) q0[e] = cmat32[(h*16 + j)*9 + e];
    #pragma unroll
    for (int e=0;e<4;e++) q1[e] = cmat32[(h*16 + j)*9 + 4 + e];
    unsigned* dst = (unsigned*)(plTbf + ((size_t)(h*32 + ib)*512 + jb*16 + j)*16);
    *(u32x4*)dst       = q0;
    *((u32x4*)dst + 1) = q1;
  }
}

// ================= K2: projection GEMM + points (64 blocks x 256) =================
__global__ void k2_projpoints(const float* __restrict__ Rm, const float* __restrict__ tv,
    char* __restrict__ ws){
  unsigned short* snbf  = (unsigned short*)(ws + OFF_SNBF);
  float*          proj  = (float*)(ws + OFF_PROJ);
  float*          qpb   = (float*)(ws + OFF_QP);
  unsigned short* kfrag = (unsigned short*)(ws + OFF_KFRAG);
  unsigned short* vfrag = (unsigned short*)(ws + OFF_VFRAG);
  float*          kn2T  = (float*)(ws + OFF_KN2);
  unsigned short* wcfrag= (unsigned short*)(ws + OFF_WCF);
  const int bid = blockIdx.x, tid = threadIdx.x;
  const int w = tid>>6, lane = tid&63, il = lane&15, ig = lane>>4;
  int ib = bid >> 1, half = bid & 1;
  int i0 = ib*16;
  bf16x8 afr[12];
  #pragma unroll
  for (int kt=0;kt<12;kt++)
    afr[kt] = *(const bf16x8*)(snbf + (i0+il)*384 + kt*32 + ig*8);
  int w2 = half*4 + w;
  for (int nt = w2; nt < 72; nt += 8){
    f32x4 acc = {0.f,0.f,0.f,0.f};
    #pragma unroll
    for (int kt=0;kt<12;kt++){
      bf16x8 b = *(const bf16x8*)(wcfrag + ((size_t)(nt*12+kt)*64 + lane)*8);
      acc = MFMA16(afr[kt], b, acc);
    }
    #pragma unroll
    for (int r=0;r<4;r++)
      proj[(size_t)(i0 + ig*4 + r)*1152 + nt*16 + il] = acc[r];
  }
  __threadfence();
  __syncthreads();
  if (tid < 96){
    int rr = half*8 + tid/12, h = tid % 12;
    int l = i0 + rr;
    float Rl[9], tl[3];
    #pragma unroll
    for (int e=0;e<9;e++) Rl[e] = Rm[l*9+e];
    #pragma unroll
    for (int e=0;e<3;e++) tl[e] = tv[l*3+e];
    const float* prow = proj + (size_t)l*1152;
    #pragma unroll
    for (int p=0;p<4;p++){
      float lx = prow[576 + h*12 + p*3+0];
      float ly = prow[576 + h*12 + p*3+1];
      float lz = prow[576 + h*12 + p*3+2];
      qpb[((size_t)l*12+h)*12 + p*3+0] = Rl[0]*lx + Rl[1]*ly + Rl[2]*lz + tl[0];
      qpb[((size_t)l*12+h)*12 + p*3+1] = Rl[3]*lx + Rl[4]*ly + Rl[5]*lz + tl[1];
      qpb[((size_t)l*12+h)*12 + p*3+2] = Rl[6]*lx + Rl[7]*ly + Rl[8]*lz + tl[2];
    }
    float kp[12]; float kn2 = 0.f;
    #pragma unroll
    for (int p=0;p<4;p++){
      float lx = prow[720 + h*12 + p*3+0];
      float ly = prow[720 + h*12 + p*3+1];
      float lz = prow[720 + h*12 + p*3+2];
      float cx = Rl[0]*lx + Rl[1]*ly + Rl[2]*lz + tl[0];
      float cy = Rl[3]*lx + Rl[4]*ly + Rl[5]*lz + tl[1];
      float cz = Rl[6]*lx + Rl[7]*ly + Rl[8]*lz + tl[2];
      kp[p*3+0]=cx; kp[p*3+1]=cy; kp[p*3+2]=cz;
      kn2 += cx*cx + cy*cy + cz*cz;
    }
    kn2T[h*512 + l] = kn2;
    {
      int jt = l>>4, jl = l&15;
      #pragma unroll
      for (int k=0;k<32;k++){
        float f = (k<16) ? prow[192 + h*16 + k] : ((k<28) ? kp[k-16] : 0.f);
        kfrag[((size_t)(h*32+jt)*64 + 16*(k>>3) + jl)*8 + (k&7)] = f2bf(f);
      }
    }
    float vp[24];
    #pragma unroll
    for (int p=0;p<8;p++){
      float lx = prow[864 + h*24 + p*3+0];
      float ly = prow[864 + h*24 + p*3+1];
      float lz = prow[864 + h*24 + p*3+2];
      vp[p*3+0] = Rl[0]*lx + Rl[1]*ly + Rl[2]*lz + tl[0];
      vp[p*3+1] = Rl[3]*lx + Rl[4]*ly + Rl[5]*lz + tl[1];
      vp[p*3+2] = Rl[6]*lx + Rl[7]*ly + Rl[8]*lz + tl[2];
    }
    {
      int jc = l>>5, jin = l&31;
      int qq = (jin&15)>>2;
      int rv = (jin&3) + ((jin>>4)<<2);
      #pragma unroll
      for (int dd=0;dd<48;dd++){
        float f = (dd<16) ? prow[384 + h*16 + dd] : ((dd<40) ? vp[dd-16] : 0.f);
        int dt = dd>>4, d_ = dd&15;
        vfrag[((size_t)((h*16+jc)*3+dt)*64 + 16*qq + d_)*8 + rv] = f2bf(f);
      }
    }
  }
}

// ================= K3: attention (plT tile staged in LDS) =================
__global__ __launch_bounds__(512) void k3_attn(char* __restrict__ ws){
  float*          proj  = (float*)(ws + OFF_PROJ);
  float*          qpb   = (float*)(ws + OFF_QP);
  unsigned short* kfrag = (unsigned short*)(ws + OFF_KFRAG);
  unsigned short* vfrag = (unsigned short*)(ws + OFF_VFRAG);
  float*          kn2T  = (float*)(ws + OFF_KN2);
  unsigned short* plTbf = (unsigned short*)(ws + OFF_PLT);
  float*          obuf  = (float*)(ws + OFF_OBUF);
  float*          wbuf  = (float*)(ws + OFF_WBUF);

  __shared__ union {
    unsigned short ptile[512*20];                                      // 20480 B
    struct { float red[8][16]; float gsum[16]; float osum[8][64][13]; } a;  // 27200 B
  } sm;

  const int u = blockIdx.x, tid = threadIdx.x;
  const int w = tid>>6, lane = tid&63, il = lane&15, ig = lane>>4;
  const int h = u >> 5, ib = u & 31;
  const int i0 = ib*16;

  // ---- stage plT tile [512 j][16 i] -> LDS (row stride 20 u16) ----
  {
    const unsigned long long* s8 =
      (const unsigned long long*)(plTbf + (size_t)(h*32 + ib)*8192);
    int j = tid;
    unsigned long long a0 = s8[j*4+0], a1 = s8[j*4+1], a2 = s8[j*4+2], a3 = s8[j*4+3];
    unsigned long long* d = (unsigned long long*)&sm.ptile[j*20];
    d[0]=a0; d[1]=a1; d[2]=a2; d[3]=a3;
  }
  float wh = wbuf[h];
  float wneg = -0.5f*wh;
  bf16x8 qfrag;
  #pragma unroll
  for (int r=0;r<8;r++){
    int k = ig*8 + r; float f;
    if (k < 16)      f = proj[(size_t)(i0+il)*1152 + h*16 + k]*0.25f;
    else if (k < 28) f = qpb[((size_t)(i0+il)*12 + h)*12 + (k-16)]*wh;
    else             f = 0.f;
    qfrag[r] = (short)f2bf(f);
  }
  __syncthreads();   // ptile staged

  // ---- QK^T (S^T tiles), C0 from LDS ----
  int jt0 = w*4;
  f32x4 sv[4];
  const unsigned short* kbase = kfrag + (size_t)(h*32)*512;
  const float* kbn = kn2T + h*512;
  #pragma unroll
  for (int jj=0;jj<4;jj++){
    int jt = jt0+jj;
    bf16x8 kf = *(const bf16x8*)(kbase + (size_t)(jt*64 + lane)*8);
    f32x4 c0;
    #pragma unroll
    for (int r=0;r<4;r++){
      int j = jt*16 + ig*4 + r;
      c0[r] = bf2f(sm.ptile[j*20 + il]) + wneg*kbn[j];
    }
    sv[jj] = MFMA16(kf, qfrag, c0);
  }
  float mx = -3.0e38f;
  #pragma unroll
  for (int jj=0;jj<4;jj++)
    #pragma unroll
    for (int r=0;r<4;r++) mx = fmaxf(mx, sv[jj][r]);
  mx = fmaxf(mx, __shfl_xor(mx,16));
  mx = fmaxf(mx, __shfl_xor(mx,32));
  __syncthreads();   // all ptile reads done; union reuse is now safe
  if (lane < 16) sm.a.red[w][lane] = mx;
  __syncthreads();
  float gm = sm.a.red[0][il];
  #pragma unroll
  for (int ww=1;ww<8;ww++) gm = fmaxf(gm, sm.a.red[ww][il]);
  __syncthreads();
  float sum = 0.f;
  #pragma unroll
  for (int jj=0;jj<4;jj++)
    #pragma unroll
    for (int r=0;r<4;r++){ float p = __expf(sv[jj][r]-gm); sv[jj][r]=p; sum+=p; }
  sum += __shfl_xor(sum,16);
  sum += __shfl_xor(sum,32);
  if (lane < 16) sm.a.red[w][lane] = sum;
  __syncthreads();
  float gs = 0.f;
  #pragma unroll
  for (int ww=0;ww<8;ww++) gs += sm.a.red[ww][il];
  if (w == 0 && lane < 16) sm.a.gsum[lane] = gs;
  // ---- partial O^T = V^T @ P^T ----
  f32x4 o0={0.f,0.f,0.f,0.f}, o1=o0, o2=o0;
  const unsigned short* vbase = vfrag + (size_t)(h*16)*3*512;
  #pragma unroll
  for (int jcl=0;jcl<2;jcl++){
    int jc = w*2 + jcl;
    bf16x8 pfrag;
    #pragma unroll
    for (int r=0;r<8;r++) pfrag[r] = (short)f2bf(sv[2*jcl + (r>>2)][r&3]);
    bf16x8 v0 = *(const bf16x8*)(vbase + (size_t)((jc*3+0)*64 + lane)*8);
    bf16x8 v1 = *(const bf16x8*)(vbase + (size_t)((jc*3+1)*64 + lane)*8);
    bf16x8 v2 = *(const bf16x8*)(vbase + (size_t)((jc*3+2)*64 + lane)*8);
    o0 = MFMA16(v0, pfrag, o0);
    o1 = MFMA16(v1, pfrag, o1);
    o2 = MFMA16(v2, pfrag, o2);
  }
  #pragma unroll
  for (int r=0;r<4;r++){
    sm.a.osum[w][lane][r]   = o0[r];
    sm.a.osum[w][lane][4+r] = o1[r];
    sm.a.osum[w][lane][8+r] = o2[r];
  }
  __syncthreads();
  for (int idx = tid; idx < 640; idx += 512){
    int i = idx & 15, d = idx >> 4;
    int seg = d >> 4, dr = d & 15;
    int lx = ((dr>>2) << 4) + i;
    int c = seg*4 + (dr & 3);
    float v = 0.f;
    #pragma unroll
    for (int ww=0;ww<8;ww++) v += sm.a.osum[ww][lx][c];
    obuf[(size_t)(i0+i)*480 + h*40 + d] = v / sm.a.gsum[i];
  }
}

// ================= K4: cat + output GEMM (32 blocks x 256) =================
#define CATS 584   // row stride in u16; 584*2=1168 B = 73*16 -> 16B-aligned rows
__global__ __launch_bounds__(256) void k4_catout(
    const float* __restrict__ s, const float* __restrict__ Rm, const float* __restrict__ tv,
    const float* __restrict__ bo, float* __restrict__ out, char* __restrict__ ws){
  float*          obuf  = (float*)(ws + OFF_OBUF);
  unsigned short* wofrag= (unsigned short*)(ws + OFF_WOF);
  __shared__ unsigned short cat[16*CATS];
  const int u = blockIdx.x, tid = threadIdx.x;
  const int w = tid>>6, lane = tid&63, il = lane&15, ig = lane>>4;
  int i0 = u*16;
  if (tid < 192){
    int rr = tid/12, hh = tid - rr*12;
    int l = i0 + rr;
    float Rl[9], tl[3];
    #pragma unroll
    for (int e=0;e<9;e++) Rl[e] = Rm[l*9+e];
    #pragma unroll
    for (int e=0;e<3;e++) tl[e] = tv[l*3+e];
    const float* orow = obuf + (size_t)l*480 + hh*40;
    #pragma unroll
    for (int d=0;d<16;d++) cat[rr*CATS + hh*16 + d] = f2bf(orow[d]);
    #pragma unroll
    for (int p=0;p<8;p++){
      float oy0 = orow[16 + p*3 + 0] - tl[0];
      float oy1 = orow[16 + p*3 + 1] - tl[1];
      float oy2 = orow[16 + p*3 + 2] - tl[2];
      float px = Rl[0]*oy0 + Rl[3]*oy1 + Rl[6]*oy2;
      float py = Rl[1]*oy0 + Rl[4]*oy1 + Rl[7]*oy2;
      float pz = Rl[2]*oy0 + Rl[5]*oy1 + Rl[8]*oy2;
      int cb = 192 + (hh*8+p)*3;
      cat[rr*CATS + cb+0] = f2bf(px);
      cat[rr*CATS + cb+1] = f2bf(py);
      cat[rr*CATS + cb+2] = f2bf(pz);
      cat[rr*CATS + 480 + hh*8 + p] = f2bf(sqrtf(px*px + py*py + pz*pz + 1e-8f));
    }
  }
  __syncthreads();
  for (int nt = w; nt < 24; nt += 4){
    int n = nt*16 + il;
    f32x4 acc = {0.f,0.f,0.f,0.f};
    #pragma unroll
    for (int kt=0;kt<18;kt++){
      bf16x8 a = *(const bf16x8*)(&cat[il*CATS + kt*32 + ig*8]);
      bf16x8 b = *(const bf16x8*)(wofrag + ((size_t)(nt*18+kt)*64 + lane)*8);
      acc = MFMA16(a, b, acc);
    }
    float bv = bo[n];
    #pragma unroll
    for (int r=0;r<4;r++){
      int row = i0 + ig*4 + r;
      out[(size_t)row*384 + n] = s[(size_t)row*384 + n] + bv + acc[r];
    }
  }
}

extern "C" void kernel_launch(void* const* d_in, const int* in_sizes, int n_in,
                              void* d_out, int out_size, void* d_ws, size_t ws_size,
                              hipStream_t stream) {
  const float* s   = (const float*)d_in[0];
  const float* z   = (const float*)d_in[1];
  const float* R   = (const float*)d_in[2];
  const float* t   = (const float*)d_in[3];
  const float* g_s = (const float*)d_in[4];
  const float* b_s = (const float*)d_in[5];
  const float* g_z = (const float*)d_in[6];
  const float* b_z = (const float*)d_in[7];
  const float* Wq  = (const float*)d_in[8];
  const float* Wk  = (const float*)d_in[9];
  const float* Wv  = (const float*)d_in[10];
  const float* Wqp = (const float*)d_in[11];
  const float* Wkp = (const float*)d_in[12];
  const float* Wvp = (const float*)d_in[13];
  const float* Wpb = (const float*)d_in[14];
  const float* pw  = (const float*)d_in[15];
  const float* Wo  = (const float*)d_in[16];
  const float* bo  = (const float*)d_in[17];
  float* out = (float*)d_out;
  char* ws = (char*)d_ws;

  k1_prep_pairbias<<<1024, 256, 0, stream>>>(s, g_s, b_s, z,
      Wq, Wk, Wv, Wqp, Wkp, Wvp, Wpb, pw, Wo, g_z, b_z, ws);
  k2_projpoints<<<64, 256, 0, stream>>>(R, t, ws);
  k3_attn<<<384, 512, 0, stream>>>(ws);
  k4_catout<<<32, 256, 0, stream>>>(s, R, t, bo, out, ws);
}

// Round 11
// 101.743 us; speedup vs baseline: 1.2490x; 1.0054x over previous
//
#include <hip/hip_runtime.h>

typedef float f32x4 __attribute__((ext_vector_type(4)));
typedef unsigned u32x4 __attribute__((ext_vector_type(4)));
typedef short bf16x8 __attribute__((ext_vector_type(8)));

#define MFMA16(a,b,c) __builtin_amdgcn_mfma_f32_16x16x32_bf16((a),(b),(c),0,0,0)

__device__ __forceinline__ unsigned short f2bf(float f){
  unsigned int u = __builtin_bit_cast(unsigned int, f);
  u += 0x7FFFu + ((u>>16)&1u);
  return (unsigned short)(u>>16);
}
__device__ __forceinline__ float bf2f(unsigned short u){
  return __builtin_bit_cast(float, ((unsigned int)u)<<16);
}

// ---------------- ws layout (bytes) ----------------
#define OFF_SNBF  0u          // 512*384*2      = 393216
#define OFF_PROJ  393216u     // 512*1152*4     = 2359296
#define OFF_QP    2752512u    // 512*144*4      = 294912
#define OFF_KFRAG 3047424u    // 12*32*64*8*2   = 393216
#define OFF_VFRAG 3440640u    // 12*16*3*64*8*2 = 589824
#define OFF_KN2   4030464u    // 12*512*4       = 24576
#define OFF_PLT   4055040u    // 12*32*512*16*2 = 6291456 (bf16, tiled [h][ib][j][16])
#define OFF_OBUF  10346496u   // 512*480*4      = 983040
#define OFF_WCF   11329536u   // 72*12*64*8*2   = 884736
#define OFF_WOF   12214272u   // 24*18*64*8*2   = 442368
#define OFF_WBUF  12656640u   // 12*4 (pad 256)

// ================= K1: prep + pairbias (block = one 16x16 (ib,jb) tile) =================
// Pairbias unit = (i, jb): LN over 16 j-rows of z[i] (8 KB contiguous) + @Wpb via MFMA.
// R11: fully-coalesced global loads (lane-linear, 16 full lines/instr) into registers,
// bounced through a per-wave padded LDS buffer ([16][132] dwords, stride 528 B) to
// restore the (row=il) lane layout for LN+MFMA. 3-stage pipeline hides HBM latency.

#define ZROW 132   // dwords per staged row (128 + 4 pad); 528 B, 16B-aligned

__global__ __launch_bounds__(256) void k1_prep_pairbias(
    const float* __restrict__ s, const float* __restrict__ g_s, const float* __restrict__ b_s,
    const float* __restrict__ z,
    const float* __restrict__ Wq, const float* __restrict__ Wk, const float* __restrict__ Wv,
    const float* __restrict__ Wqp, const float* __restrict__ Wkp, const float* __restrict__ Wvp,
    const float* __restrict__ Wpb, const float* __restrict__ pw, const float* __restrict__ Wo,
    const float* __restrict__ g_z, const float* __restrict__ b_z,
    char* __restrict__ ws){
  unsigned short* snbf  = (unsigned short*)(ws + OFF_SNBF);
  unsigned short* plTbf = (unsigned short*)(ws + OFF_PLT);
  unsigned short* wcfrag= (unsigned short*)(ws + OFF_WCF);
  unsigned short* wofrag= (unsigned short*)(ws + OFF_WOF);
  float*          wbuf  = (float*)(ws + OFF_WBUF);
  const int bid = blockIdx.x, tid = threadIdx.x;
  const int w = tid>>6, lane = tid&63, il = lane&15, ig = lane>>4;

  __shared__ float zbuf[4][16*ZROW];          // 33792 B: per-wave staging
  __shared__ unsigned short wf_l[4][64][8];   // 4096 B: Wpb bf16 frag per (c, lane)
  __shared__ float gz_l[4][32];               // 512 B
  __shared__ float bz_l[4][32];               // 512 B
  __shared__ unsigned cmat32[12*16*9];        // 6912 B: [h][j][18 u16] (16 + 2 pad)
  unsigned short* cmat = (unsigned short*)cmat32;

  // ---- LDS constant setup ----
  {
    int c = tid >> 6, ln = tid & 63;
    int ili = ln & 15, igi = ln >> 4;
    #pragma unroll
    for (int r=0;r<8;r++){
      int cc = c*32 + igi*8 + r;
      wf_l[c][ln][r] = (ili<12) ? f2bf(Wpb[cc*12 + ili]) : (unsigned short)0;
    }
    if (tid < 128){
      int cc2 = tid >> 5, k2 = tid & 31;
      gz_l[cc2][k2] = g_z[cc2*32 + k2];
      bz_l[cc2][k2] = b_z[cc2*32 + k2];
    }
  }

  if (bid < 192){
    int u = bid;
    if (u < 24){
      // wcfrag: k-chunk, coalesced along n
      int k = u*16 + (tid>>4), nloc = tid & 15;
      int kt = k>>5, kin = k&31;
      int fl = (kin>>3)*16 + nloc, r = kin&7;
      #pragma unroll 4
      for (int nt=0; nt<72; nt++){
        int n = nt*16 + nloc;
        float v;
        if      (n < 192) v = Wq [k*192 + n];
        else if (n < 384) v = Wk [k*192 + (n-192)];
        else if (n < 576) v = Wv [k*192 + (n-384)];
        else if (n < 720) v = Wqp[k*144 + (n-576)];
        else if (n < 864) v = Wkp[k*144 + (n-720)];
        else              v = Wvp[k*288 + (n-864)];
        wcfrag[((size_t)(nt*12+kt)*64 + fl)*8 + r] = f2bf(v);
      }
    } else if (u < 60){
      int k = (u-24)*16 + (tid>>4), nloc = tid & 15;
      int kt = k>>5, kin = k&31;
      int fl = (kin>>3)*16 + nloc, r = kin&7;
      #pragma unroll 4
      for (int nt=0; nt<24; nt++){
        int n = nt*16 + nloc;
        wofrag[((size_t)(nt*18+kt)*64 + fl)*8 + r] = f2bf(Wo[k*384 + n]);
      }
    } else if (u < 188){
      int l = (u-60)*4 + w;
      float v[6]; float sum=0.f, ss=0.f;
      #pragma unroll
      for (int k=0;k<6;k++){
        float x = s[l*384 + lane + 64*k];
        v[k]=x; sum += x; ss = fmaf(x,x,ss);
      }
      #pragma unroll
      for (int m=1;m<64;m<<=1){ sum += __shfl_xor(sum,m); ss += __shfl_xor(ss,m); }
      float mu = sum*(1.f/384.f);
      float var = ss*(1.f/384.f) - mu*mu;
      float rs = rsqrtf(var + 1e-5f);
      #pragma unroll
      for (int k=0;k<6;k++){
        int c = lane + 64*k;
        snbf[l*384 + c] = f2bf((v[k]-mu)*rs*g_s[c] + b_s[c]);
      }
    } else if (u == 188){
      if (tid < 12) wbuf[tid] = log1pf(expf(pw[tid]));
    }
  }
  __syncthreads();   // LDS constants ready

  // ---- pairbias tile (ib, jb): 4 units/wave, coalesced-load + LDS-bounce pipeline ----
  int ib = bid >> 5, jb = bid & 31;
  float* zb = &zbuf[w][0];
  const float* zu0 = z + (((size_t)(ib*16 + w*4))*512 + jb*16)*128;
  f32x4 zr[8];

  // gload: lane-linear coalesced (unit byte k*1024 + lane*16)
  #define PB_GLOAD(E) { \
    const float* zu_ = zu0 + (size_t)(E)*65536; \
    _Pragma("unroll") \
    for (int k=0;k<8;k++) zr[k] = *(const f32x4*)(zu_ + k*256 + lane*4); }
  // swrite: row 2k+(lane>>5), col (lane&31)*4 floats, padded stride
  #define PB_SWRITE() { \
    _Pragma("unroll") \
    for (int k=0;k<8;k++) \
      *(f32x4*)(zb + (2*k + (lane>>5))*ZROW + (lane&31)*4) = zr[k]; }
  // compute: LN + @Wpb from LDS, MFMA, cmat store (col iloc)
  #define PB_COMPUTE(E) { \
    f32x4 zv[8]; \
    _Pragma("unroll") \
    for (int c=0;c<4;c++){ \
      zv[2*c]   = *(const f32x4*)(zb + il*ZROW + c*32 + ig*8); \
      zv[2*c+1] = *(const f32x4*)(zb + il*ZROW + c*32 + ig*8 + 4); \
    } \
    float sum=0.f, ss=0.f; \
    _Pragma("unroll") \
    for (int m=0;m<8;m++) \
      _Pragma("unroll") \
      for (int e2=0;e2<4;e2++){ float x = zv[m][e2]; sum += x; ss = fmaf(x,x,ss); } \
    sum += __shfl_xor(sum,16); sum += __shfl_xor(sum,32); \
    ss  += __shfl_xor(ss,16);  ss  += __shfl_xor(ss,32); \
    float mu  = sum*(1.f/128.f); \
    float var = ss*(1.f/128.f) - mu*mu; \
    float rs  = rsqrtf(var + 1e-5f); \
    f32x4 acc = {0.f,0.f,0.f,0.f}; \
    _Pragma("unroll") \
    for (int c=0;c<4;c++){ \
      f32x4 ga = *(const f32x4*)&gz_l[c][ig*8]; \
      f32x4 gb = *(const f32x4*)&gz_l[c][ig*8+4]; \
      f32x4 ba = *(const f32x4*)&bz_l[c][ig*8]; \
      f32x4 bb = *(const f32x4*)&bz_l[c][ig*8+4]; \
      bf16x8 wfc = *(const bf16x8*)&wf_l[c][lane][0]; \
      bf16x8 zf; \
      _Pragma("unroll") \
      for (int r=0;r<8;r++){ \
        float xv = (r<4)? zv[2*c][r&3] : zv[2*c+1][r&3]; \
        float gv = (r<4)? ga[r&3] : gb[r&3]; \
        float bv = (r<4)? ba[r&3] : bb[r&3]; \
        zf[r] = (short)f2bf((xv-mu)*(rs*gv) + bv); \
      } \
      acc = MFMA16(zf, wfc, acc); \
    } \
    if (il < 12){ \
      _Pragma("unroll") \
      for (int r=0;r<4;r++) \
        cmat[(il*16 + ig*4 + r)*18 + (w*4+(E))] = f2bf(acc[r]); \
    } }

  PB_GLOAD(0)
  PB_SWRITE()
  PB_GLOAD(1)
  PB_COMPUTE(0)
  PB_SWRITE()
  PB_GLOAD(2)
  PB_COMPUTE(1)
  PB_SWRITE()
  PB_GLOAD(3)
  PB_COMPUTE(2)
  PB_SWRITE()
  PB_COMPUTE(3)

  __syncthreads();
  if (tid < 192){
    int h = tid >> 4, j = tid & 15;
    u32x4 q0, q1;
    #pragma unroll
    for (int e=0;e<4;e++) q0[e] = cmat32[(h*16 + j)*9 + e];
    #pragma unroll
    for (int e=0;e<4;e++) q1[e] = cmat32[(h*16 + j)*9 + 4 + e];
    unsigned* dst = (unsigned*)(plTbf + ((size_t)(h*32 + ib)*512 + jb*16 + j)*16);
    *(u32x4*)dst       = q0;
    *((u32x4*)dst + 1) = q1;
  }
}

// ================= K2: projection GEMM + points (64 blocks x 256) =================
__global__ void k2_projpoints(const float* __restrict__ Rm, const float* __restrict__ tv,
    char* __restrict__ ws){
  unsigned short* snbf  = (unsigned short*)(ws + OFF_SNBF);
  float*          proj  = (float*)(ws + OFF_PROJ);
  float*          qpb   = (float*)(ws + OFF_QP);
  unsigned short* kfrag = (unsigned short*)(ws + OFF_KFRAG);
  unsigned short* vfrag = (unsigned short*)(ws + OFF_VFRAG);
  float*          kn2T  = (float*)(ws + OFF_KN2);
  unsigned short* wcfrag= (unsigned short*)(ws + OFF_WCF);
  const int bid = blockIdx.x, tid = threadIdx.x;
  const int w = tid>>6, lane = tid&63, il = lane&15, ig = lane>>4;
  int ib = bid >> 1, half = bid & 1;
  int i0 = ib*16;
  bf16x8 afr[12];
  #pragma unroll
  for (int kt=0;kt<12;kt++)
    afr[kt] = *(const bf16x8*)(snbf + (i0+il)*384 + kt*32 + ig*8);
  int w2 = half*4 + w;
  for (int nt = w2; nt < 72; nt += 8){
    f32x4 acc = {0.f,0.f,0.f,0.f};
    #pragma unroll
    for (int kt=0;kt<12;kt++){
      bf16x8 b = *(const bf16x8*)(wcfrag + ((size_t)(nt*12+kt)*64 + lane)*8);
      acc = MFMA16(afr[kt], b, acc);
    }
    #pragma unroll
    for (int r=0;r<4;r++)
      proj[(size_t)(i0 + ig*4 + r)*1152 + nt*16 + il] = acc[r];
  }
  __threadfence();
  __syncthreads();
  if (tid < 96){
    int rr = half*8 + tid/12, h = tid % 12;
    int l = i0 + rr;
    float Rl[9], tl[3];
    #pragma unroll
    for (int e=0;e<9;e++) Rl[e] = Rm[l*9+e];
    #pragma unroll
    for (int e=0;e<3;e++) tl[e] = tv[l*3+e];
    const float* prow = proj + (size_t)l*1152;
    #pragma unroll
    for (int p=0;p<4;p++){
      float lx = prow[576 + h*12 + p*3+0];
      float ly = prow[576 + h*12 + p*3+1];
      float lz = prow[576 + h*12 + p*3+2];
      qpb[((size_t)l*12+h)*12 + p*3+0] = Rl[0]*lx + Rl[1]*ly + Rl[2]*lz + tl[0];
      qpb[((size_t)l*12+h)*12 + p*3+1] = Rl[3]*lx + Rl[4]*ly + Rl[5]*lz + tl[1];
      qpb[((size_t)l*12+h)*12 + p*3+2] = Rl[6]*lx + Rl[7]*ly + Rl[8]*lz + tl[2];
    }
    float kp[12]; float kn2 = 0.f;
    #pragma unroll
    for (int p=0;p<4;p++){
      float lx = prow[720 + h*12 + p*3+0];
      float ly = prow[720 + h*12 + p*3+1];
      float lz = prow[720 + h*12 + p*3+2];
      float cx = Rl[0]*lx + Rl[1]*ly + Rl[2]*lz + tl[0];
      float cy = Rl[3]*lx + Rl[4]*ly + Rl[5]*lz + tl[1];
      float cz = Rl[6]*lx + Rl[7]*ly + Rl[8]*lz + tl[2];
      kp[p*3+0]=cx; kp[p*3+1]=cy; kp[p*3+2]=cz;
      kn2 += cx*cx + cy*cy + cz*cz;
    }
    kn2T[h*512 + l] = kn2;
    {
      int jt = l>>4, jl = l&15;
      #pragma unroll
      for (int k=0;k<32;k++){
        float f = (k<16) ? prow[192 + h*16 + k] : ((k<28) ? kp[k-16] : 0.f);
        kfrag[((size_t)(h*32+jt)*64 + 16*(k>>3) + jl)*8 + (k&7)] = f2bf(f);
      }
    }
    float vp[24];
    #pragma unroll
    for (int p=0;p<8;p++){
      float lx = prow[864 + h*24 + p*3+0];
      float ly = prow[864 + h*24 + p*3+1];
      float lz = prow[864 + h*24 + p*3+2];
      vp[p*3+0] = Rl[0]*lx + Rl[1]*ly + Rl[2]*lz + tl[0];
      vp[p*3+1] = Rl[3]*lx + Rl[4]*ly + Rl[5]*lz + tl[1];
      vp[p*3+2] = Rl[6]*lx + Rl[7]*ly + Rl[8]*lz + tl[2];
    }
    {
      int jc = l>>5, jin = l&31;
      int qq = (jin&15)>>2;
      int rv = (jin&3) + ((jin>>4)<<2);
      #pragma unroll
      for (int dd=0;dd<48;dd++){
        float f = (dd<16) ? prow[384 + h*16 + dd] : ((dd<40) ? vp[dd-16] : 0.f);
        int dt = dd>>4, d_ = dd&15;
        vfrag[((size_t)((h*16+jc)*3+dt)*64 + 16*qq + d_)*8 + rv] = f2bf(f);
      }
    }
  }
}

// ================= K3: attention (plT tile staged in LDS) =================
__global__ __launch_bounds__(512) void k3_attn(char* __restrict__ ws){
  float*          proj  = (float*)(ws + OFF_PROJ);
  float*          qpb   = (float*)(ws + OFF_QP);
  unsigned short* kfrag = (unsigned short*)(ws + OFF_KFRAG);
  unsigned short* vfrag = (unsigned short*)(ws + OFF_VFRAG);
  float*          kn2T  = (float*)(ws + OFF_KN2);
  unsigned short* plTbf = (unsigned short*)(ws + OFF_PLT);
  float*          obuf  = (float*)(ws + OFF_OBUF);
  float*          wbuf  = (float*)(ws + OFF_WBUF);

  __shared__ union {
    unsigned short ptile[512*20];                                      // 20480 B
    struct { float red[8][16]; float gsum[16]; float osum[8][64][13]; } a;  // 27200 B
  } sm;

  const int u = blockIdx.x, tid = threadIdx.x;
  const int w = tid>>6, lane = tid&63, il = lane&15, ig = lane>>4;
  const int h = u >> 5, ib = u & 31;
  const int i0 = ib*16;

  // ---- stage plT tile [512 j][16 i] -> LDS (row stride 20 u16) ----
  {
    const unsigned long long* s8 =
      (const unsigned long long*)(plTbf + (size_t)(h*32 + ib)*8192);
    int j = tid;
    unsigned long long a0 = s8[j*4+0], a1 = s8[j*4+1], a2 = s8[j*4+2], a3 = s8[j*4+3];
    unsigned long long* d = (unsigned long long*)&sm.ptile[j*20];
    d[0]=a0; d[1]=a1; d[2]=a2; d[3]=a3;
  }
  float wh = wbuf[h];
  float wneg = -0.5f*wh;
  bf16x8 qfrag;
  #pragma unroll
  for (int r=0;r<8;r++){
    int k = ig*8 + r; float f;
    if (k < 16)      f = proj[(size_t)(i0+il)*1152 + h*16 + k]*0.25f;
    else if (k < 28) f = qpb[((size_t)(i0+il)*12 + h)*12 + (k-16)]*wh;
    else             f = 0.f;
    qfrag[r] = (short)f2bf(f);
  }
  __syncthreads();   // ptile staged

  // ---- QK^T (S^T tiles), C0 from LDS ----
  int jt0 = w*4;
  f32x4 sv[4];
  const unsigned short* kbase = kfrag + (size_t)(h*32)*512;
  const float* kbn = kn2T + h*512;
  #pragma unroll
  for (int jj=0;jj<4;jj++){
    int jt = jt0+jj;
    bf16x8 kf = *(const bf16x8*)(kbase + (size_t)(jt*64 + lane)*8);
    f32x4 c0;
    #pragma unroll
    for (int r=0;r<4;r++){
      int j = jt*16 + ig*4 + r;
      c0[r] = bf2f(sm.ptile[j*20 + il]) + wneg*kbn[j];
    }
    sv[jj] = MFMA16(kf, qfrag, c0);
  }
  float mx = -3.0e38f;
  #pragma unroll
  for (int jj=0;jj<4;jj++)
    #pragma unroll
    for (int r=0;r<4;r++) mx = fmaxf(mx, sv[jj][r]);
  mx = fmaxf(mx, __shfl_xor(mx,16));
  mx = fmaxf(mx, __shfl_xor(mx,32));
  __syncthreads();   // all ptile reads done; union reuse is now safe
  if (lane < 16) sm.a.red[w][lane] = mx;
  __syncthreads();
  float gm = sm.a.red[0][il];
  #pragma unroll
  for (int ww=1;ww<8;ww++) gm = fmaxf(gm, sm.a.red[ww][il]);
  __syncthreads();
  float sum = 0.f;
  #pragma unroll
  for (int jj=0;jj<4;jj++)
    #pragma unroll
    for (int r=0;r<4;r++){ float p = __expf(sv[jj][r]-gm); sv[jj][r]=p; sum+=p; }
  sum += __shfl_xor(sum,16);
  sum += __shfl_xor(sum,32);
  if (lane < 16) sm.a.red[w][lane] = sum;
  __syncthreads();
  float gs = 0.f;
  #pragma unroll
  for (int ww=0;ww<8;ww++) gs += sm.a.red[ww][il];
  if (w == 0 && lane < 16) sm.a.gsum[lane] = gs;
  // ---- partial O^T = V^T @ P^T ----
  f32x4 o0={0.f,0.f,0.f,0.f}, o1=o0, o2=o0;
  const unsigned short* vbase = vfrag + (size_t)(h*16)*3*512;
  #pragma unroll
  for (int jcl=0;jcl<2;jcl++){
    int jc = w*2 + jcl;
    bf16x8 pfrag;
    #pragma unroll
    for (int r=0;r<8;r++) pfrag[r] = (short)f2bf(sv[2*jcl + (r>>2)][r&3]);
    bf16x8 v0 = *(const bf16x8*)(vbase + (size_t)((jc*3+0)*64 + lane)*8);
    bf16x8 v1 = *(const bf16x8*)(vbase + (size_t)((jc*3+1)*64 + lane)*8);
    bf16x8 v2 = *(const bf16x8*)(vbase + (size_t)((jc*3+2)*64 + lane)*8);
    o0 = MFMA16(v0, pfrag, o0);
    o1 = MFMA16(v1, pfrag, o1);
    o2 = MFMA16(v2, pfrag, o2);
  }
  #pragma unroll
  for (int r=0;r<4;r++){
    sm.a.osum[w][lane][r]   = o0[r];
    sm.a.osum[w][lane][4+r] = o1[r];
    sm.a.osum[w][lane][8+r] = o2[r];
  }
  __syncthreads();
  for (int idx = tid; idx < 640; idx += 512){
    int i = idx & 15, d = idx >> 4;
    int seg = d >> 4, dr = d & 15;
    int lx = ((dr>>2) << 4) + i;
    int c = seg*4 + (dr & 3);
    float v = 0.f;
    #pragma unroll
    for (int ww=0;ww<8;ww++) v += sm.a.osum[ww][lx][c];
    obuf[(size_t)(i0+i)*480 + h*40 + d] = v / sm.a.gsum[i];
  }
}

// ================= K4: cat + output GEMM (32 blocks x 256) =================
#define CATS 584   // row stride in u16; 584*2=1168 B = 73*16 -> 16B-aligned rows
__global__ __launch_bounds__(256) void k4_catout(
    const float* __restrict__ s, const float* __restrict__ Rm, const float* __restrict__ tv,
    const float* __restrict__ bo, float* __restrict__ out, char* __restrict__ ws){
  float*          obuf  = (float*)(ws + OFF_OBUF);
  unsigned short* wofrag= (unsigned short*)(ws + OFF_WOF);
  __shared__ unsigned short cat[16*CATS];
  const int u = blockIdx.x, tid = threadIdx.x;
  const int w = tid>>6, lane = tid&63, il = lane&15, ig = lane>>4;
  int i0 = u*16;
  if (tid < 192){
    int rr = tid/12, hh = tid - rr*12;
    int l = i0 + rr;
    float Rl[9], tl[3];
    #pragma unroll
    for (int e=0;e<9;e++) Rl[e] = Rm[l*9+e];
    #pragma unroll
    for (int e=0;e<3;e++) tl[e] = tv[l*3+e];
    const float* orow = obuf + (size_t)l*480 + hh*40;
    #pragma unroll
    for (int d=0;d<16;d++) cat[rr*CATS + hh*16 + d] = f2bf(orow[d]);
    #pragma unroll
    for (int p=0;p<8;p++){
      float oy0 = orow[16 + p*3 + 0] - tl[0];
      float oy1 = orow[16 + p*3 + 1] - tl[1];
      float oy2 = orow[16 + p*3 + 2] - tl[2];
      float px = Rl[0]*oy0 + Rl[3]*oy1 + Rl[6]*oy2;
      float py = Rl[1]*oy0 + Rl[4]*oy1 + Rl[7]*oy2;
      float pz = Rl[2]*oy0 + Rl[5]*oy1 + Rl[8]*oy2;
      int cb = 192 + (hh*8+p)*3;
      cat[rr*CATS + cb+0] = f2bf(px);
      cat[rr*CATS + cb+1] = f2bf(py);
      cat[rr*CATS + cb+2] = f2bf(pz);
      cat[rr*CATS + 480 + hh*8 + p] = f2bf(sqrtf(px*px + py*py + pz*pz + 1e-8f));
    }
  }
  __syncthreads();
  for (int nt = w; nt < 24; nt += 4){
    int n = nt*16 + il;
    f32x4 acc = {0.f,0.f,0.f,0.f};
    #pragma unroll
    for (int kt=0;kt<18;kt++){
      bf16x8 a = *(const bf16x8*)(&cat[il*CATS + kt*32 + ig*8]);
      bf16x8 b = *(const bf16x8*)(wofrag + ((size_t)(nt*18+kt)*64 + lane)*8);
      acc = MFMA16(a, b, acc);
    }
    float bv = bo[n];
    #pragma unroll
    for (int r=0;r<4;r++){
      int row = i0 + ig*4 + r;
      out[(size_t)row*384 + n] = s[(size_t)row*384 + n] + bv + acc[r];
    }
  }
}

extern "C" void kernel_launch(void* const* d_in, const int* in_sizes, int n_in,
                              void* d_out, int out_size, void* d_ws, size_t ws_size,
                              hipStream_t stream) {
  const float* s   = (const float*)d_in[0];
  const float* z   = (const float*)d_in[1];
  const float* R   = (const float*)d_in[2];
  const float* t   = (const float*)d_in[3];
  const float* g_s = (const float*)d_in[4];
  const float* b_s = (const float*)d_in[5];
  const float* g_z = (const float*)d_in[6];
  const float* b_z = (const float*)d_in[7];
  const float* Wq  = (const float*)d_in[8];
  const float* Wk  = (const float*)d_in[9];
  const float* Wv  = (const float*)d_in[10];
  const float* Wqp = (const float*)d_in[11];
  const float* Wkp = (const float*)d_in[12];
  const float* Wvp = (const float*)d_in[13];
  const float* Wpb = (const float*)d_in[14];
  const float* pw  = (const float*)d_in[15];
  const float* Wo  = (const float*)d_in[16];
  const float* bo  = (const float*)d_in[17];
  float* out = (float*)d_out;
  char* ws = (char*)d_ws;

  k1_prep_pairbias<<<1024, 256, 0, stream>>>(s, g_s, b_s, z,
      Wq, Wk, Wv, Wqp, Wkp, Wvp, Wpb, pw, Wo, g_z, b_z, ws);
  k2_projpoints<<<64, 256, 0, stream>>>(R, t, ws);
  k3_attn<<<384, 512, 0, stream>>>(ws);
  k4_catout<<<32, 256, 0, stream>>>(s, R, t, bo, out, ws);
}